// Round 1
// baseline (306.221 us; speedup 1.0000x reference)
//
#include <hip/hip_runtime.h>
#include <hip/hip_bf16.h>

// Problem constants (fixed by setup_inputs)
#define N_SAMP 1024
#define BD     2048
#define LATENT_D 1024
#define NCLS   64
#define HW     49   // 7*7

// ---------------------------------------------------------------------------
// Kernel 1: adaptive avg pool (mean over 49 contiguous floats per (n,d) pair)
// Block = 256 threads handles 256 contiguous pairs = 12544 contiguous floats.
// Coalesced float4 stage into LDS, then each thread sums its own 49.
// stride 49 (odd) -> lane t reads bank (17*t + k) % 32 -> 2-way max = free.
// ---------------------------------------------------------------------------
__global__ __launch_bounds__(256) void pool_kernel(const float* __restrict__ feat,
                                                   float* __restrict__ x0) {
    __shared__ float buf[256 * HW];                  // 50176 B
    const int b = blockIdx.x;
    const float4* src = reinterpret_cast<const float4*>(feat + (size_t)b * (256 * HW));
    float4* dst = reinterpret_cast<float4*>(buf);
    #pragma unroll
    for (int i = threadIdx.x; i < (256 * HW) / 4; i += 256) dst[i] = src[i];
    __syncthreads();
    const float* p = buf + threadIdx.x * HW;
    float s = 0.f;
    #pragma unroll
    for (int k = 0; k < HW; ++k) s += p[k];
    x0[(size_t)b * 256 + threadIdx.x] = s * (1.0f / 49.0f);
}

// ---------------------------------------------------------------------------
// Kernel 2: fc1 GEMM fp32:  X[n][l] = relu( sum_k x0[n][k]*W[l][k] + bias[l] )
// A = x0 [1024][2048], W [1024][2048] (both K-contiguous -> A*B^T).
// 64x64 tile, BK=32, 256 threads (16x16), 4x4 per thread.
// LDS stored K-major: As[k][row] so inner loop uses ds_read_b128.
// ---------------------------------------------------------------------------
#define BK 32
#define LDP 68   // padded row stride (words); 68*4 B is 16B-aligned, spreads banks
__global__ __launch_bounds__(256) void fc1_kernel(const float* __restrict__ A,
                                                  const float* __restrict__ W,
                                                  const float* __restrict__ bias,
                                                  float* __restrict__ X) {
    __shared__ float As[BK][LDP];
    __shared__ float Bs[BK][LDP];
    const int K = BD;
    const int bm = blockIdx.y, bn = blockIdx.x;
    const int tid = threadIdx.x;
    const int tx = tid & 15, ty = tid >> 4;

    float acc[4][4] = {};

    for (int k0 = 0; k0 < K; k0 += BK) {
        // stage 64x32 A-tile and 64x32 B-tile; 512 float4 slots each
        #pragma unroll
        for (int s = tid; s < 512; s += 256) {
            const int c4 = s & 7;        // which float4 along K
            const int row = s >> 3;      // tile row
            const float4 av = *reinterpret_cast<const float4*>(
                &A[(size_t)(bm * 64 + row) * K + k0 + c4 * 4]);
            const float4 bv = *reinterpret_cast<const float4*>(
                &W[(size_t)(bn * 64 + row) * K + k0 + c4 * 4]);
            As[c4 * 4 + 0][row] = av.x; As[c4 * 4 + 1][row] = av.y;
            As[c4 * 4 + 2][row] = av.z; As[c4 * 4 + 3][row] = av.w;
            Bs[c4 * 4 + 0][row] = bv.x; Bs[c4 * 4 + 1][row] = bv.y;
            Bs[c4 * 4 + 2][row] = bv.z; Bs[c4 * 4 + 3][row] = bv.w;
        }
        __syncthreads();
        #pragma unroll
        for (int k = 0; k < BK; ++k) {
            const float4 av = *reinterpret_cast<const float4*>(&As[k][ty * 4]);
            const float4 bv = *reinterpret_cast<const float4*>(&Bs[k][tx * 4]);
            const float ar[4] = {av.x, av.y, av.z, av.w};
            const float br[4] = {bv.x, bv.y, bv.z, bv.w};
            #pragma unroll
            for (int i = 0; i < 4; ++i)
                #pragma unroll
                for (int j = 0; j < 4; ++j)
                    acc[i][j] = fmaf(ar[i], br[j], acc[i][j]);
        }
        __syncthreads();
    }

    const int row0 = bm * 64 + ty * 4;
    const int col0 = bn * 64 + tx * 4;
    #pragma unroll
    for (int i = 0; i < 4; ++i) {
        #pragma unroll
        for (int j = 0; j < 4; ++j) {
            float v = acc[i][j] + bias[col0 + j];
            X[(size_t)(row0 + i) * LATENT_D + col0 + j] = v > 0.f ? v : 0.f;
        }
    }
}

// ---------------------------------------------------------------------------
// Kernel 3: classification heads + sigmoid + ordinal label decode.
// Block per sample n, 128 threads = 2 waves (wave0 = pos head, wave1 = orient).
// Thread = one class logit (dot over 1024). Label: ballot(logit>0), run length
// of trailing ones from bit 0 == sum(cumprod(pred>0.5)).
// ---------------------------------------------------------------------------
__global__ __launch_bounds__(128) void cls_kernel(const float* __restrict__ x,
                                                  const float* __restrict__ wp,
                                                  const float* __restrict__ bp,
                                                  const float* __restrict__ wo,
                                                  const float* __restrict__ bo,
                                                  float* __restrict__ pose_cls,
                                                  int* __restrict__ idx_out) {
    const int n = blockIdx.x;
    __shared__ float xs[LATENT_D];
    for (int i = threadIdx.x; i < LATENT_D; i += 128)
        xs[i] = x[(size_t)n * LATENT_D + i];
    __syncthreads();

    const int head = threadIdx.x >> 6;   // 0 = pos, 1 = orient
    const int c = threadIdx.x & 63;
    const float* w = (head ? wo : wp) + (size_t)c * LATENT_D;
    float s = head ? bo[c] : bp[c];
    const float4* w4 = reinterpret_cast<const float4*>(w);
    #pragma unroll 8
    for (int i = 0; i < LATENT_D / 4; ++i) {
        const float4 a = w4[i];
        s += a.x * xs[4 * i] + a.y * xs[4 * i + 1] + a.z * xs[4 * i + 2] + a.w * xs[4 * i + 3];
    }

    const float sig = 1.0f / (1.0f + expf(-s));
    // pose_cls layout [N][C][2]
    pose_cls[(size_t)n * (NCLS * 2) + c * 2 + head] = sig;

    const unsigned long long mask = __ballot(s > 0.0f);   // bit c = pred_c > 0.5
    if (c == 0) {
        const unsigned long long inv = ~mask;
        const int run = inv ? __builtin_ctzll(inv) : 64;   // leading run of ones
        const int lab = run - 1;
        idx_out[n * 2 + head] = lab > 0 ? lab : 0;
    }
}

// ---------------------------------------------------------------------------
// Kernel 4: hard-routed expert heads. One wave per output element (n,k).
// pose[n][k] = reg_w[idx][k] . x[n] + reg_b[idx][k];  k<3 -> pos, k>=3 -> orient
// ---------------------------------------------------------------------------
__global__ __launch_bounds__(256) void expert_kernel(const float* __restrict__ x,
                                                     const float* __restrict__ wpos,
                                                     const float* __restrict__ bpos,
                                                     const float* __restrict__ wori,
                                                     const float* __restrict__ bori,
                                                     const int* __restrict__ idx,
                                                     float* __restrict__ pose) {
    const int gwave = (blockIdx.x * 256 + threadIdx.x) >> 6;  // 0 .. N*7-1
    const int lane = threadIdx.x & 63;
    const int n = gwave / 7;
    const int k = gwave % 7;

    const float* w;
    float b;
    if (k < 3) {
        const int e = idx[n * 2 + 0];
        w = wpos + (size_t)(e * 3 + k) * LATENT_D;
        b = bpos[e * 3 + k];
    } else {
        const int e = idx[n * 2 + 1];
        const int kk = k - 3;
        w = wori + (size_t)(e * 4 + kk) * LATENT_D;
        b = bori[e * 4 + kk];
    }

    const float4* w4 = reinterpret_cast<const float4*>(w);
    const float4* x4 = reinterpret_cast<const float4*>(x + (size_t)n * LATENT_D);
    float s = 0.f;
    #pragma unroll
    for (int i = lane; i < LATENT_D / 4; i += 64) {
        const float4 a = w4[i];
        const float4 c = x4[i];
        s += a.x * c.x + a.y * c.y + a.z * c.z + a.w * c.w;
    }
    #pragma unroll
    for (int off = 32; off > 0; off >>= 1) s += __shfl_down(s, off);
    if (lane == 0) pose[(size_t)n * 7 + k] = s + b;
}

// ---------------------------------------------------------------------------
extern "C" void kernel_launch(void* const* d_in, const int* in_sizes, int n_in,
                              void* d_out, int out_size, void* d_ws, size_t ws_size,
                              hipStream_t stream) {
    const float* feat   = (const float*)d_in[0];
    const float* fc1_w  = (const float*)d_in[1];
    const float* fc1_b  = (const float*)d_in[2];
    const float* cpw    = (const float*)d_in[3];
    const float* cpb    = (const float*)d_in[4];
    const float* cow    = (const float*)d_in[5];
    const float* cob    = (const float*)d_in[6];
    const float* rpw    = (const float*)d_in[7];
    const float* rpb    = (const float*)d_in[8];
    const float* row_   = (const float*)d_in[9];
    const float* rob    = (const float*)d_in[10];

    float* out = (float*)d_out;
    float* pose     = out;            // [1024][7]
    float* pose_cls = out + (size_t)N_SAMP * 7;   // [1024][64][2]

    char* ws = (char*)d_ws;
    float* x0  = (float*)(ws);                                  // [1024][2048]  8 MB
    float* x   = (float*)(ws + (size_t)N_SAMP * BD * 4);        // [1024][1024]  4 MB
    int*   idx = (int*)  (ws + (size_t)N_SAMP * BD * 4 + (size_t)N_SAMP * LATENT_D * 4);

    // 1. pool
    pool_kernel<<<(N_SAMP * BD) / 256, 256, 0, stream>>>(feat, x0);
    // 2. fc1 + relu
    dim3 g2(LATENT_D / 64, N_SAMP / 64);
    fc1_kernel<<<g2, 256, 0, stream>>>(x0, fc1_w, fc1_b, x);
    // 3. cls heads + labels
    cls_kernel<<<N_SAMP, 128, 0, stream>>>(x, cpw, cpb, cow, cob, pose_cls, idx);
    // 4. expert heads
    expert_kernel<<<(N_SAMP * 7) / 4, 256, 0, stream>>>(x, rpw, rpb, row_, rob, idx, pose);
}

// Round 2
// 209.520 us; speedup vs baseline: 1.4615x; 1.4615x over previous
//
#include <hip/hip_runtime.h>
#include <hip/hip_bf16.h>

#define N_SAMP   1024
#define BD       2048
#define LATENT_D 1024
#define NCLS     64
#define HW       49

typedef __attribute__((ext_vector_type(8))) short bf16x8;
typedef __attribute__((ext_vector_type(4))) float f32x4;
typedef unsigned short u16;

// ---------------------------------------------------------------------------
// Split-bf16 global layout: logical [row][k] (k < 2048), stored tiled:
//   segment (kg = k>>5, row) is 32 ushorts (64 B) at index (kg*1024+row)*32,
//   byte within segment swizzled: c2 = (ke*2) ^ (((row>>1)&3)<<4).
// This makes a 128-row x 32-k tile a single contiguous 8 KB chunk whose linear
// copy into LDS (global_load_lds) lands pre-swizzled for conflict-light
// ds_read_b128 fragment reads (G21: source perm == read perm).
// ---------------------------------------------------------------------------
__device__ __forceinline__ size_t split_idx(int row, int k) {
    const int kg = k >> 5, ke = k & 31;
    const int c2 = (ke * 2) ^ (((row >> 1) & 3) << 4);
    return ((size_t)(kg * 1024 + row) * 32) + (c2 >> 1);
}

__device__ __forceinline__ void split3(float v, u16* p0, u16* p1, u16* p2, size_t idx) {
    __hip_bfloat16 b0 = __float2bfloat16(v);
    float r = v - __bfloat162float(b0);
    __hip_bfloat16 b1 = __float2bfloat16(r);
    r -= __bfloat162float(b1);
    __hip_bfloat16 b2 = __float2bfloat16(r);
    p0[idx] = *(u16*)&b0;
    p1[idx] = *(u16*)&b1;
    p2[idx] = *(u16*)&b2;
}

// ---------------------------------------------------------------------------
// Kernel 1: avg-pool 7x7 -> split3 -> swizzled bf16 arrays A0/A1/A2
// block b: n = b>>3, d = (b&7)*256 + tid  (256 contiguous (n,d) pairs)
// ---------------------------------------------------------------------------
__global__ __launch_bounds__(256) void pool_kernel(const float* __restrict__ feat,
                                                   u16* __restrict__ a0,
                                                   u16* __restrict__ a1,
                                                   u16* __restrict__ a2) {
    __shared__ float buf[256 * HW];
    const int b = blockIdx.x;
    const float4* src = reinterpret_cast<const float4*>(feat + (size_t)b * (256 * HW));
    float4* dst = reinterpret_cast<float4*>(buf);
    #pragma unroll
    for (int i = threadIdx.x; i < (256 * HW) / 4; i += 256) dst[i] = src[i];
    __syncthreads();
    const float* p = buf + threadIdx.x * HW;
    float s = 0.f;
    #pragma unroll
    for (int k = 0; k < HW; ++k) s += p[k];
    const float v = s * (1.0f / 49.0f);
    const int n = b >> 3;
    const int d = (b & 7) * 256 + threadIdx.x;
    split3(v, a0, a1, a2, split_idx(n, d));
}

// ---------------------------------------------------------------------------
// Kernel 2: fc1_w fp32 -> split3 swizzled bf16 arrays B0/B1/B2
// ---------------------------------------------------------------------------
__global__ __launch_bounds__(256) void wsplit_kernel(const float* __restrict__ W,
                                                     u16* __restrict__ b0,
                                                     u16* __restrict__ b1,
                                                     u16* __restrict__ b2) {
    const int row = blockIdx.x >> 3;
    const int d = (blockIdx.x & 7) * 256 + threadIdx.x;
    split3(W[(size_t)row * BD + d], b0, b1, b2, split_idx(row, d));
}

// ---------------------------------------------------------------------------
// Kernel 3: fc1 GEMM via 6 split-product bf16 MFMAs (error ~2^-27 rel).
// Tile 128x128, BK=32, 4 waves each owning a 64x64 quadrant (4x4 frags of
// 16x16x32). Split-K over blockIdx.z; fp32 partials to ws.
// LDS: 6 buffers x [128][32] ushort = 48 KB, single-buffered; split-K grid
// puts 2 blocks/CU so cross-block overlap hides the barrier drain (m114).
// ---------------------------------------------------------------------------
#define GLL16(g, l) __builtin_amdgcn_global_load_lds( \
    (const __attribute__((address_space(1))) void*)(g), \
    (__attribute__((address_space(3))) void*)(l), 16, 0, 0)

__global__ __launch_bounds__(256, 1) void fc1_mfma(
    const u16* __restrict__ A0, const u16* __restrict__ A1, const u16* __restrict__ A2,
    const u16* __restrict__ B0, const u16* __restrict__ B1, const u16* __restrict__ B2,
    float* __restrict__ part, int ksteps) {
    __shared__ u16 lds[6 * 4096];   // 48 KB
    const int bn = blockIdx.x, bm = blockIdx.y, kz = blockIdx.z;
    const int tid = threadIdx.x, lane = tid & 63, wv = tid >> 6;
    const int wrow = (wv >> 1) * 64, wcol = (wv & 1) * 64;
    const int r15 = lane & 15, khi = lane >> 4;

    f32x4 acc[4][4];
    #pragma unroll
    for (int i = 0; i < 4; ++i)
        #pragma unroll
        for (int j = 0; j < 4; ++j) acc[i][j] = (f32x4){0.f, 0.f, 0.f, 0.f};

    const u16* gA[3] = {A0, A1, A2};
    const u16* gB[3] = {B0, B1, B2};
    const int kg0 = kz * ksteps;

    for (int ks = 0; ks < ksteps; ++ks) {
        const int kg = kg0 + ks;
        // ---- stage: 6 buffers, each 128 rows x 32 ushort; wave wv does rows
        // [wv*32, wv*32+32) = 2 x 1KB global_load_lds insts per buffer.
        #pragma unroll
        for (int s = 0; s < 3; ++s) {
            const u16* g = gA[s] + ((size_t)(kg * 1024 + bm * 128 + wv * 32) * 32) + lane * 8;
            u16* l = lds + s * 4096 + wv * 1024 + lane * 8;
            GLL16(g, l);
            GLL16(g + 512, l + 512);
        }
        #pragma unroll
        for (int s = 0; s < 3; ++s) {
            const u16* g = gB[s] + ((size_t)(kg * 1024 + bn * 128 + wv * 32) * 32) + lane * 8;
            u16* l = lds + (3 + s) * 4096 + wv * 1024 + lane * 8;
            GLL16(g, l);
            GLL16(g + 512, l + 512);
        }
        __syncthreads();   // drains vmcnt before reads

        // ---- fragment loads (ds_read_b128, ~2-way conflict with swizzle)
        bf16x8 af[4][3], bf[4][3];
        #pragma unroll
        for (int i = 0; i < 4; ++i) {
            const int rowA = wrow + i * 16 + r15;
            const int offA = rowA * 64 + ((khi * 16) ^ (((rowA >> 1) & 3) << 4));
            const int rowB = wcol + i * 16 + r15;
            const int offB = rowB * 64 + ((khi * 16) ^ (((rowB >> 1) & 3) << 4));
            #pragma unroll
            for (int s = 0; s < 3; ++s) {
                af[i][s] = *(const bf16x8*)((const char*)(lds + s * 4096) + offA);
                bf[i][s] = *(const bf16x8*)((const char*)(lds + (3 + s) * 4096) + offB);
            }
        }
        // ---- 6 split products; product-outer order keeps 16 independent
        // accumulator chains between reuses of the same acc register.
        #pragma unroll
        for (int p = 0; p < 6; ++p) {
            const int pa = (p == 0 || p == 1 || p == 4) ? 0 : (p == 5 ? 2 : 1);
            const int pb = (p == 0 || p == 2 || p == 5) ? 0 : (p == 4 ? 2 : 1);
            #pragma unroll
            for (int i = 0; i < 4; ++i)
                #pragma unroll
                for (int j = 0; j < 4; ++j)
                    acc[i][j] = __builtin_amdgcn_mfma_f32_16x16x32_bf16(
                        af[i][pa], bf[j][pb], acc[i][j], 0, 0, 0);
        }
        __syncthreads();   // all reads done before next stage overwrites
    }

    // ---- epilogue: fp32 partials [kz][1024][1024]
    float* pt = part + (size_t)kz * (LATENT_D * N_SAMP);
    #pragma unroll
    for (int i = 0; i < 4; ++i) {
        const int row0 = bm * 128 + wrow + i * 16 + khi * 4;
        #pragma unroll
        for (int j = 0; j < 4; ++j) {
            const int col = bn * 128 + wcol + j * 16 + r15;
            #pragma unroll
            for (int q = 0; q < 4; ++q)
                pt[(size_t)(row0 + q) * LATENT_D + col] = acc[i][j][q];
        }
    }
}

// ---------------------------------------------------------------------------
// Kernel 4: reduce split-K partials + bias + ReLU -> x fp32 [1024][1024]
// ---------------------------------------------------------------------------
__global__ __launch_bounds__(256) void reduce_kernel(const float* __restrict__ part,
                                                     const float* __restrict__ bias,
                                                     float* __restrict__ x, int nsplit) {
    const int i = blockIdx.x * 256 + threadIdx.x;     // float4 index, 262144 total
    const float4* p = reinterpret_cast<const float4*>(part);
    float4 s = p[i];
    for (int z = 1; z < nsplit; ++z) {
        const float4 t = p[(size_t)z * 262144 + i];
        s.x += t.x; s.y += t.y; s.z += t.z; s.w += t.w;
    }
    const float4 b = reinterpret_cast<const float4*>(bias)[i & 255];
    s.x = fmaxf(s.x + b.x, 0.f); s.y = fmaxf(s.y + b.y, 0.f);
    s.z = fmaxf(s.z + b.z, 0.f); s.w = fmaxf(s.w + b.w, 0.f);
    reinterpret_cast<float4*>(x)[i] = s;
}

// ---------------------------------------------------------------------------
// Kernel 5: cls heads + sigmoid + ordinal label decode (unchanged, fp32)
// ---------------------------------------------------------------------------
__global__ __launch_bounds__(128) void cls_kernel(const float* __restrict__ x,
                                                  const float* __restrict__ wp,
                                                  const float* __restrict__ bp,
                                                  const float* __restrict__ wo,
                                                  const float* __restrict__ bo,
                                                  float* __restrict__ pose_cls,
                                                  int* __restrict__ idx_out) {
    const int n = blockIdx.x;
    __shared__ float xs[LATENT_D];
    for (int i = threadIdx.x; i < LATENT_D; i += 128)
        xs[i] = x[(size_t)n * LATENT_D + i];
    __syncthreads();

    const int head = threadIdx.x >> 6;
    const int c = threadIdx.x & 63;
    const float* w = (head ? wo : wp) + (size_t)c * LATENT_D;
    float s = head ? bo[c] : bp[c];
    const float4* w4 = reinterpret_cast<const float4*>(w);
    #pragma unroll 8
    for (int i = 0; i < LATENT_D / 4; ++i) {
        const float4 a = w4[i];
        s += a.x * xs[4 * i] + a.y * xs[4 * i + 1] + a.z * xs[4 * i + 2] + a.w * xs[4 * i + 3];
    }

    const float sig = 1.0f / (1.0f + expf(-s));
    pose_cls[(size_t)n * (NCLS * 2) + c * 2 + head] = sig;

    const unsigned long long mask = __ballot(s > 0.0f);
    if (c == 0) {
        const unsigned long long inv = ~mask;
        const int run = inv ? __builtin_ctzll(inv) : 64;
        const int lab = run - 1;
        idx_out[n * 2 + head] = lab > 0 ? lab : 0;
    }
}

// ---------------------------------------------------------------------------
// Kernel 6: hard-routed expert heads (unchanged)
// ---------------------------------------------------------------------------
__global__ __launch_bounds__(256) void expert_kernel(const float* __restrict__ x,
                                                     const float* __restrict__ wpos,
                                                     const float* __restrict__ bpos,
                                                     const float* __restrict__ wori,
                                                     const float* __restrict__ bori,
                                                     const int* __restrict__ idx,
                                                     float* __restrict__ pose) {
    const int gwave = (blockIdx.x * 256 + threadIdx.x) >> 6;
    const int lane = threadIdx.x & 63;
    const int n = gwave / 7;
    const int k = gwave % 7;

    const float* w;
    float b;
    if (k < 3) {
        const int e = idx[n * 2 + 0];
        w = wpos + (size_t)(e * 3 + k) * LATENT_D;
        b = bpos[e * 3 + k];
    } else {
        const int e = idx[n * 2 + 1];
        const int kk = k - 3;
        w = wori + (size_t)(e * 4 + kk) * LATENT_D;
        b = bori[e * 4 + kk];
    }

    const float4* w4 = reinterpret_cast<const float4*>(w);
    const float4* x4 = reinterpret_cast<const float4*>(x + (size_t)n * LATENT_D);
    float s = 0.f;
    #pragma unroll
    for (int i = lane; i < LATENT_D / 4; i += 64) {
        const float4 a = w4[i];
        const float4 c = x4[i];
        s += a.x * c.x + a.y * c.y + a.z * c.z + a.w * c.w;
    }
    #pragma unroll
    for (int off = 32; off > 0; off >>= 1) s += __shfl_down(s, off);
    if (lane == 0) pose[(size_t)n * 7 + k] = s + b;
}

// ---------------------------------------------------------------------------
extern "C" void kernel_launch(void* const* d_in, const int* in_sizes, int n_in,
                              void* d_out, int out_size, void* d_ws, size_t ws_size,
                              hipStream_t stream) {
    const float* feat   = (const float*)d_in[0];
    const float* fc1_w  = (const float*)d_in[1];
    const float* fc1_b  = (const float*)d_in[2];
    const float* cpw    = (const float*)d_in[3];
    const float* cpb    = (const float*)d_in[4];
    const float* cow    = (const float*)d_in[5];
    const float* cob    = (const float*)d_in[6];
    const float* rpw    = (const float*)d_in[7];
    const float* rpb    = (const float*)d_in[8];
    const float* row_   = (const float*)d_in[9];
    const float* rob    = (const float*)d_in[10];

    float* out = (float*)d_out;
    float* pose     = out;                          // [1024][7]
    float* pose_cls = out + (size_t)N_SAMP * 7;     // [1024][64][2]

    char* ws = (char*)d_ws;
    const size_t MB4 = (size_t)4 << 20;
    u16* A0 = (u16*)(ws);
    u16* A1 = (u16*)(ws + 1 * MB4);
    u16* A2 = (u16*)(ws + 2 * MB4);
    u16* Bs0 = (u16*)(ws + 3 * MB4);
    u16* Bs1 = (u16*)(ws + 4 * MB4);
    u16* Bs2 = (u16*)(ws + 5 * MB4);
    float* part = (float*)(ws + 6 * MB4);

    // pick largest split-K whose partial buffers fit the workspace
    int nsplit = 8;
    while (nsplit > 1 &&
           6 * MB4 + (size_t)(nsplit + 1) * MB4 + 8192 > ws_size) nsplit >>= 1;
    float* x   = (float*)(ws + 6 * MB4 + (size_t)nsplit * MB4);
    int*   idx = (int*)  (ws + 6 * MB4 + (size_t)(nsplit + 1) * MB4);
    const int ksteps = 64 / nsplit;   // K-groups (of 32) per split block

    wsplit_kernel<<<8192, 256, 0, stream>>>(fc1_w, Bs0, Bs1, Bs2);
    pool_kernel<<<(N_SAMP * BD) / 256, 256, 0, stream>>>(feat, A0, A1, A2);
    fc1_mfma<<<dim3(8, 8, nsplit), 256, 0, stream>>>(A0, A1, A2, Bs0, Bs1, Bs2, part, ksteps);
    reduce_kernel<<<1024, 256, 0, stream>>>(part, fc1_b, x, nsplit);
    cls_kernel<<<N_SAMP, 128, 0, stream>>>(x, cpw, cpb, cow, cob, pose_cls, idx);
    expert_kernel<<<(N_SAMP * 7) / 4, 256, 0, stream>>>(x, rpw, rpb, row_, rob, idx, pose);
}

// Round 3
// 169.471 us; speedup vs baseline: 1.8069x; 1.2363x over previous
//
#include <hip/hip_runtime.h>
#include <hip/hip_bf16.h>

#define N_SAMP   1024
#define BD       2048
#define LATENT_D 1024
#define NCLS     64
#define HW       49

typedef __attribute__((ext_vector_type(8))) short bf16x8;
typedef __attribute__((ext_vector_type(4))) float f32x4;
typedef unsigned short u16;

// ---------------------------------------------------------------------------
// Split-bf16 tiled+swizzled layout, generalized over row count:
//   segment (kg = k>>5, row) is 32 ushorts (64 B) at ((kg*rows + row)*32),
//   byte within segment: c2 = (ke*2) ^ (((row>>1)&3)<<4).
// A 128-row x 32-k tile is one contiguous 8 KB chunk; linear global_load_lds
// lands pre-swizzled for conflict-light ds_read_b128 (G21 source==read perm).
// ---------------------------------------------------------------------------
__device__ __forceinline__ size_t split_idx_r(int row, int k, int rows) {
    const int kg = k >> 5, ke = k & 31;
    const int c2 = (ke * 2) ^ (((row >> 1) & 3) << 4);
    return ((size_t)(kg * rows + row) * 32) + (c2 >> 1);
}

__device__ __forceinline__ void split3(float v, u16* p0, u16* p1, u16* p2, size_t idx) {
    __hip_bfloat16 b0 = __float2bfloat16(v);
    float r = v - __bfloat162float(b0);
    __hip_bfloat16 b1 = __float2bfloat16(r);
    r -= __bfloat162float(b1);
    __hip_bfloat16 b2 = __float2bfloat16(r);
    p0[idx] = *(u16*)&b0;
    p1[idx] = *(u16*)&b1;
    p2[idx] = *(u16*)&b2;
}

// ---------------------------------------------------------------------------
// Kernel 1: avg-pool 7x7 -> split3 -> swizzled bf16 A0/A1/A2 (rows=1024, K=2048)
// ---------------------------------------------------------------------------
__global__ __launch_bounds__(256) void pool_kernel(const float* __restrict__ feat,
                                                   u16* __restrict__ a0,
                                                   u16* __restrict__ a1,
                                                   u16* __restrict__ a2) {
    __shared__ float buf[256 * HW];
    const int b = blockIdx.x;
    const float4* src = reinterpret_cast<const float4*>(feat + (size_t)b * (256 * HW));
    float4* dst = reinterpret_cast<float4*>(buf);
    #pragma unroll
    for (int i = threadIdx.x; i < (256 * HW) / 4; i += 256) dst[i] = src[i];
    __syncthreads();
    const float* p = buf + threadIdx.x * HW;
    float s = 0.f;
    #pragma unroll
    for (int k = 0; k < HW; ++k) s += p[k];
    const float v = s * (1.0f / 49.0f);
    const int n = b >> 3;
    const int d = (b & 7) * 256 + threadIdx.x;
    split3(v, a0, a1, a2, split_idx_r(n, d, N_SAMP));
}

// ---------------------------------------------------------------------------
// Kernel 2: fc1_w fp32 -> split3 swizzled (rows=1024, K=2048)
// ---------------------------------------------------------------------------
__global__ __launch_bounds__(256) void wsplit_kernel(const float* __restrict__ W,
                                                     u16* __restrict__ b0,
                                                     u16* __restrict__ b1,
                                                     u16* __restrict__ b2) {
    const int row = blockIdx.x >> 3;
    const int d = (blockIdx.x & 7) * 256 + threadIdx.x;
    split3(W[(size_t)row * BD + d], b0, b1, b2, split_idx_r(row, d, LATENT_D));
}

// ---------------------------------------------------------------------------
// Kernel 2b: combined cls weights [128 rows: 64 pos | 64 orient][1024] -> split3
// (rows=128, K=1024)
// ---------------------------------------------------------------------------
__global__ __launch_bounds__(256) void csplit_kernel(const float* __restrict__ Wp,
                                                     const float* __restrict__ Wo,
                                                     u16* __restrict__ c0,
                                                     u16* __restrict__ c1,
                                                     u16* __restrict__ c2) {
    const int row = blockIdx.x >> 2;                    // 0..127
    const int d = (blockIdx.x & 3) * 256 + threadIdx.x; // 0..1023
    const float v = row < 64 ? Wp[(size_t)row * LATENT_D + d]
                             : Wo[(size_t)(row - 64) * LATENT_D + d];
    split3(v, c0, c1, c2, split_idx_r(row, d, 128));
}

// ---------------------------------------------------------------------------
// Kernel 3: generalized split-bf16 MFMA GEMM (6 products, error ~2^-24 rel).
// M fixed = 1024 samples. Tile 128x128, BK=32, 4 waves x (64x64 quadrant).
// Split-K via blockIdx.z; fp32 partials [kz][1024][ldc].
// fc1 path: rowsA=1024, rowsB=1024, ldc=1024 (bit-identical to round-2 kernel).
// cls path: rowsA=1024 (X splits), rowsB=128, ldc=128, bn=0 only.
// ---------------------------------------------------------------------------
#define GLL16(g, l) __builtin_amdgcn_global_load_lds( \
    (const __attribute__((address_space(1))) void*)(g), \
    (__attribute__((address_space(3))) void*)(l), 16, 0, 0)

__global__ __launch_bounds__(256, 1) void split_mfma(
    const u16* __restrict__ A0, const u16* __restrict__ A1, const u16* __restrict__ A2,
    const u16* __restrict__ B0, const u16* __restrict__ B1, const u16* __restrict__ B2,
    float* __restrict__ part, int ksteps, int rowsA, int rowsB, int ldc) {
    __shared__ u16 lds[6 * 4096];   // 48 KB
    const int bn = blockIdx.x, bm = blockIdx.y, kz = blockIdx.z;
    const int tid = threadIdx.x, lane = tid & 63, wv = tid >> 6;
    const int wrow = (wv >> 1) * 64, wcol = (wv & 1) * 64;
    const int r15 = lane & 15, khi = lane >> 4;

    f32x4 acc[4][4];
    #pragma unroll
    for (int i = 0; i < 4; ++i)
        #pragma unroll
        for (int j = 0; j < 4; ++j) acc[i][j] = (f32x4){0.f, 0.f, 0.f, 0.f};

    const u16* gA[3] = {A0, A1, A2};
    const u16* gB[3] = {B0, B1, B2};
    const int kg0 = kz * ksteps;

    for (int ks = 0; ks < ksteps; ++ks) {
        const int kg = kg0 + ks;
        #pragma unroll
        for (int s = 0; s < 3; ++s) {
            const u16* g = gA[s] + ((size_t)(kg * rowsA + bm * 128 + wv * 32) * 32) + lane * 8;
            u16* l = lds + s * 4096 + wv * 1024 + lane * 8;
            GLL16(g, l);
            GLL16(g + 512, l + 512);
        }
        #pragma unroll
        for (int s = 0; s < 3; ++s) {
            const u16* g = gB[s] + ((size_t)(kg * rowsB + bn * 128 + wv * 32) * 32) + lane * 8;
            u16* l = lds + (3 + s) * 4096 + wv * 1024 + lane * 8;
            GLL16(g, l);
            GLL16(g + 512, l + 512);
        }
        __syncthreads();

        bf16x8 af[4][3], bf[4][3];
        #pragma unroll
        for (int i = 0; i < 4; ++i) {
            const int rowA = wrow + i * 16 + r15;
            const int offA = rowA * 64 + ((khi * 16) ^ (((rowA >> 1) & 3) << 4));
            const int rowB = wcol + i * 16 + r15;
            const int offB = rowB * 64 + ((khi * 16) ^ (((rowB >> 1) & 3) << 4));
            #pragma unroll
            for (int s = 0; s < 3; ++s) {
                af[i][s] = *(const bf16x8*)((const char*)(lds + s * 4096) + offA);
                bf[i][s] = *(const bf16x8*)((const char*)(lds + (3 + s) * 4096) + offB);
            }
        }
        #pragma unroll
        for (int p = 0; p < 6; ++p) {
            const int pa = (p == 0 || p == 1 || p == 4) ? 0 : (p == 5 ? 2 : 1);
            const int pb = (p == 0 || p == 2 || p == 5) ? 0 : (p == 4 ? 2 : 1);
            #pragma unroll
            for (int i = 0; i < 4; ++i)
                #pragma unroll
                for (int j = 0; j < 4; ++j)
                    acc[i][j] = __builtin_amdgcn_mfma_f32_16x16x32_bf16(
                        af[i][pa], bf[j][pb], acc[i][j], 0, 0, 0);
        }
        __syncthreads();
    }

    float* pt = part + (size_t)kz * ((size_t)N_SAMP * ldc);
    #pragma unroll
    for (int i = 0; i < 4; ++i) {
        const int row0 = bm * 128 + wrow + i * 16 + khi * 4;
        #pragma unroll
        for (int j = 0; j < 4; ++j) {
            const int col = bn * 128 + wcol + j * 16 + r15;
            #pragma unroll
            for (int q = 0; q < 4; ++q)
                pt[(size_t)(row0 + q) * ldc + col] = acc[i][j][q];
        }
    }
}

// ---------------------------------------------------------------------------
// Kernel 4: reduce fc1 split-K partials + bias + ReLU -> x fp32, AND split3
// x into swizzled X0/X1/X2 (rows=1024, K=1024) for the cls GEMM.
// ---------------------------------------------------------------------------
__global__ __launch_bounds__(256) void reduce_fc1(const float* __restrict__ part,
                                                  const float* __restrict__ bias,
                                                  float* __restrict__ x,
                                                  u16* __restrict__ x0,
                                                  u16* __restrict__ x1,
                                                  u16* __restrict__ x2,
                                                  int nsplit) {
    const int i = blockIdx.x * 256 + threadIdx.x;     // float4 index, 262144 total
    const float4* p = reinterpret_cast<const float4*>(part);
    float4 s = p[i];
    for (int z = 1; z < nsplit; ++z) {
        const float4 t = p[(size_t)z * 262144 + i];
        s.x += t.x; s.y += t.y; s.z += t.z; s.w += t.w;
    }
    const float4 b = reinterpret_cast<const float4*>(bias)[i & 255];
    s.x = fmaxf(s.x + b.x, 0.f); s.y = fmaxf(s.y + b.y, 0.f);
    s.z = fmaxf(s.z + b.z, 0.f); s.w = fmaxf(s.w + b.w, 0.f);
    reinterpret_cast<float4*>(x)[i] = s;
    const int n = i >> 8, d0 = (i & 255) * 4;
    split3(s.x, x0, x1, x2, split_idx_r(n, d0 + 0, N_SAMP));
    split3(s.y, x0, x1, x2, split_idx_r(n, d0 + 1, N_SAMP));
    split3(s.z, x0, x1, x2, split_idx_r(n, d0 + 2, N_SAMP));
    split3(s.w, x0, x1, x2, split_idx_r(n, d0 + 3, N_SAMP));
}

// ---------------------------------------------------------------------------
// Kernel 5: decode — reduce cls split-K partials [z][1024][128] + bias,
// sigmoid -> pose_cls, ballot -> ordinal labels. Block per sample, 128 thr
// (wave 0 = pos head, wave 1 = orient head). All reads coalesced.
// ---------------------------------------------------------------------------
__global__ __launch_bounds__(128) void decode_kernel(const float* __restrict__ part2,
                                                     const float* __restrict__ bp,
                                                     const float* __restrict__ bo,
                                                     float* __restrict__ pose_cls,
                                                     int* __restrict__ idx_out,
                                                     int nsplit) {
    const int n = blockIdx.x, t = threadIdx.x;
    float s = (t < 64) ? bp[t] : bo[t - 64];
    for (int z = 0; z < nsplit; ++z)
        s += part2[(size_t)z * (N_SAMP * 128) + (size_t)n * 128 + t];
    const float sig = 1.0f / (1.0f + expf(-s));
    const int head = t >> 6, c = t & 63;
    pose_cls[(size_t)n * (NCLS * 2) + c * 2 + head] = sig;

    const unsigned long long mask = __ballot(s > 0.0f);
    if (c == 0) {
        const unsigned long long inv = ~mask;
        const int run = inv ? __builtin_ctzll(inv) : 64;
        const int lab = run - 1;
        idx_out[n * 2 + head] = lab > 0 ? lab : 0;
    }
}

// ---------------------------------------------------------------------------
// Kernel 6: hard-routed expert heads (unchanged, verified)
// ---------------------------------------------------------------------------
__global__ __launch_bounds__(256) void expert_kernel(const float* __restrict__ x,
                                                     const float* __restrict__ wpos,
                                                     const float* __restrict__ bpos,
                                                     const float* __restrict__ wori,
                                                     const float* __restrict__ bori,
                                                     const int* __restrict__ idx,
                                                     float* __restrict__ pose) {
    const int gwave = (blockIdx.x * 256 + threadIdx.x) >> 6;
    const int lane = threadIdx.x & 63;
    const int n = gwave / 7;
    const int k = gwave % 7;

    const float* w;
    float b;
    if (k < 3) {
        const int e = idx[n * 2 + 0];
        w = wpos + (size_t)(e * 3 + k) * LATENT_D;
        b = bpos[e * 3 + k];
    } else {
        const int e = idx[n * 2 + 1];
        const int kk = k - 3;
        w = wori + (size_t)(e * 4 + kk) * LATENT_D;
        b = bori[e * 4 + kk];
    }

    const float4* w4 = reinterpret_cast<const float4*>(w);
    const float4* x4 = reinterpret_cast<const float4*>(x + (size_t)n * LATENT_D);
    float s = 0.f;
    #pragma unroll
    for (int i = lane; i < LATENT_D / 4; i += 64) {
        const float4 a = w4[i];
        const float4 c = x4[i];
        s += a.x * c.x + a.y * c.y + a.z * c.z + a.w * c.w;
    }
    #pragma unroll
    for (int off = 32; off > 0; off >>= 1) s += __shfl_down(s, off);
    if (lane == 0) pose[(size_t)n * 7 + k] = s + b;
}

// ---------------------------------------------------------------------------
extern "C" void kernel_launch(void* const* d_in, const int* in_sizes, int n_in,
                              void* d_out, int out_size, void* d_ws, size_t ws_size,
                              hipStream_t stream) {
    const float* feat   = (const float*)d_in[0];
    const float* fc1_w  = (const float*)d_in[1];
    const float* fc1_b  = (const float*)d_in[2];
    const float* cpw    = (const float*)d_in[3];
    const float* cpb    = (const float*)d_in[4];
    const float* cow    = (const float*)d_in[5];
    const float* cob    = (const float*)d_in[6];
    const float* rpw    = (const float*)d_in[7];
    const float* rpb    = (const float*)d_in[8];
    const float* row_   = (const float*)d_in[9];
    const float* rob    = (const float*)d_in[10];

    float* out = (float*)d_out;
    float* pose     = out;                          // [1024][7]
    float* pose_cls = out + (size_t)N_SAMP * 7;     // [1024][64][2]

    char* ws = (char*)d_ws;
    const size_t MB = (size_t)1 << 20;
    size_t off = 0;
    auto take = [&](size_t bytes) { char* p = ws + off; off += (bytes + 255) & ~(size_t)255; return p; };

    u16* A0 = (u16*)take(4 * MB);   // 64kg x 1024 x 32 x 2B
    u16* A1 = (u16*)take(4 * MB);
    u16* A2 = (u16*)take(4 * MB);
    u16* B0 = (u16*)take(4 * MB);
    u16* B1 = (u16*)take(4 * MB);
    u16* B2 = (u16*)take(4 * MB);
    u16* C0 = (u16*)take(256 * 1024);  // 32kg x 128 x 32 x 2B
    u16* C1 = (u16*)take(256 * 1024);
    u16* C2 = (u16*)take(256 * 1024);
    u16* X0 = (u16*)take(2 * MB);   // 32kg x 1024 x 32 x 2B
    u16* X1 = (u16*)take(2 * MB);
    u16* X2 = (u16*)take(2 * MB);
    float* x = (float*)take(4 * MB);

    // fc1 split-K: pick largest nsplit whose partials fit
    int nsplit = 8;
    while (nsplit > 1 && off + (size_t)nsplit * 4 * MB + 5 * MB > ws_size) nsplit >>= 1;
    float* part = (float*)take((size_t)nsplit * 4 * MB);
    int nsplit_c = 8;
    while (nsplit_c > 1 && off + (size_t)nsplit_c * 512 * 1024 + 16 * 1024 > ws_size) nsplit_c >>= 1;
    float* part2 = (float*)take((size_t)nsplit_c * 512 * 1024);
    int* idx = (int*)take(16 * 1024);

    // independent prep
    wsplit_kernel<<<8192, 256, 0, stream>>>(fc1_w, B0, B1, B2);
    csplit_kernel<<<512, 256, 0, stream>>>(cpw, cow, C0, C1, C2);
    pool_kernel<<<(N_SAMP * BD) / 256, 256, 0, stream>>>(feat, A0, A1, A2);
    // fc1: M=1024, N=1024, K=2048
    split_mfma<<<dim3(8, 8, nsplit), 256, 0, stream>>>(
        A0, A1, A2, B0, B1, B2, part, 64 / nsplit, N_SAMP, LATENT_D, LATENT_D);
    reduce_fc1<<<1024, 256, 0, stream>>>(part, fc1_b, x, X0, X1, X2, nsplit);
    // cls: M=1024, N=128, K=1024
    split_mfma<<<dim3(1, 8, nsplit_c), 256, 0, stream>>>(
        X0, X1, X2, C0, C1, C2, part2, 32 / nsplit_c, N_SAMP, 128, 128);
    decode_kernel<<<N_SAMP, 128, 0, stream>>>(part2, cpb, cob, pose_cls, idx, nsplit_c);
    expert_kernel<<<(N_SAMP * 7) / 4, 256, 0, stream>>>(x, rpw, rpb, row_, rob, idx, pose);
}

// Round 4
// 154.417 us; speedup vs baseline: 1.9831x; 1.0975x over previous
//
#include <hip/hip_runtime.h>
#include <hip/hip_bf16.h>

#define N_SAMP   1024
#define BD       2048
#define LATENT_D 1024
#define NCLS     64
#define HW       49

typedef __attribute__((ext_vector_type(8))) _Float16 f16x8;
typedef __attribute__((ext_vector_type(4))) float f32x4;
typedef unsigned short u16;

// ---------------------------------------------------------------------------
// Split-fp16 tiled+swizzled layout (generalized over row count):
//   segment (kg = k>>5, row) = 32 ushorts (64 B) at ((kg*rows + row)*32),
//   byte within segment: c2 = (ke*2) ^ (((row>>1)&3)<<4).
// A 128-row x 32-k tile is one contiguous 8 KB chunk; linear global_load_lds
// lands pre-swizzled for conflict-light ds_read_b128 (G21 source==read perm).
// fp16 2-way split: v = h0 + h1, rel err ~2^-22 -> fp32-grade GEMM via
// 4 MFMA products (vs 6 for bf16 3-way). Verified layout from rounds 2-3.
// ---------------------------------------------------------------------------
__device__ __forceinline__ size_t split_idx_r(int row, int k, int rows) {
    const int kg = k >> 5, ke = k & 31;
    const int c2 = (ke * 2) ^ (((row >> 1) & 3) << 4);
    return ((size_t)(kg * rows + row) * 32) + (c2 >> 1);
}

__device__ __forceinline__ void split2(float v, u16* p0, u16* p1, size_t idx) {
    _Float16 h0 = (_Float16)v;
    _Float16 h1 = (_Float16)(v - (float)h0);
    p0[idx] = *(u16*)&h0;
    p1[idx] = *(u16*)&h1;
}

// ---------------------------------------------------------------------------
// Kernel 1: avg-pool 7x7 -> split2 -> swizzled fp16 A0/A1 (rows=1024, K=2048)
// ---------------------------------------------------------------------------
__global__ __launch_bounds__(256) void pool_kernel(const float* __restrict__ feat,
                                                   u16* __restrict__ a0,
                                                   u16* __restrict__ a1) {
    __shared__ float buf[256 * HW];
    const int b = blockIdx.x;
    const float4* src = reinterpret_cast<const float4*>(feat + (size_t)b * (256 * HW));
    float4* dst = reinterpret_cast<float4*>(buf);
    #pragma unroll
    for (int i = threadIdx.x; i < (256 * HW) / 4; i += 256) dst[i] = src[i];
    __syncthreads();
    const float* p = buf + threadIdx.x * HW;
    float s = 0.f;
    #pragma unroll
    for (int k = 0; k < HW; ++k) s += p[k];
    const float v = s * (1.0f / 49.0f);
    const int n = b >> 3;
    const int d = (b & 7) * 256 + threadIdx.x;
    split2(v, a0, a1, split_idx_r(n, d, N_SAMP));
}

// ---------------------------------------------------------------------------
// Kernel 2: fused weight split. Blocks [0,8192): fc1_w rows (1024r x 2048k).
// Blocks [8192, 8704): combined cls rows [64 pos | 64 orient] (128r x 1024k).
// ---------------------------------------------------------------------------
__global__ __launch_bounds__(256) void wsplit_kernel(const float* __restrict__ W,
                                                     const float* __restrict__ Wp,
                                                     const float* __restrict__ Wo,
                                                     u16* __restrict__ b0,
                                                     u16* __restrict__ b1,
                                                     u16* __restrict__ c0,
                                                     u16* __restrict__ c1) {
    const int b = blockIdx.x;
    if (b < 8192) {
        const int row = b >> 3;
        const int d = (b & 7) * 256 + threadIdx.x;
        split2(W[(size_t)row * BD + d], b0, b1, split_idx_r(row, d, LATENT_D));
    } else {
        const int b2 = b - 8192;
        const int row = b2 >> 2;                            // 0..127
        const int d = (b2 & 3) * 256 + threadIdx.x;         // 0..1023
        const float v = row < 64 ? Wp[(size_t)row * LATENT_D + d]
                                 : Wo[(size_t)(row - 64) * LATENT_D + d];
        split2(v, c0, c1, split_idx_r(row, d, 128));
    }
}

// ---------------------------------------------------------------------------
// Kernel 3: split-fp16 MFMA GEMM, 4 products, fp32-grade.
// Tile 128x128, BK=32, 4 waves x (64x64 quadrant of 4x4 16x16x32 frags).
// Double-buffered LDS (2 x 32 KB); 2-phase prefetch: ds_read cur frags ->
// issue next-tile global_load_lds -> MFMA (no mem deps, hides load latency)
// -> vmcnt(0) + barrier. One barrier per K-step (was two, zero overlap).
// Split-K via blockIdx.z; fp32 partials [kz][1024][ldc].
// ---------------------------------------------------------------------------
#define GLL16(g, l) __builtin_amdgcn_global_load_lds( \
    (const __attribute__((address_space(1))) void*)(g), \
    (__attribute__((address_space(3))) void*)(l), 16, 0, 0)

__global__ __launch_bounds__(256, 2) void split_mfma(
    const u16* __restrict__ A0, const u16* __restrict__ A1,
    const u16* __restrict__ B0, const u16* __restrict__ B1,
    float* __restrict__ part, int ksteps, int rowsA, int rowsB, int ldc) {
    __shared__ u16 lds[2][4 * 4096];   // 2 phases x (A0|A1|B0|B1) x 8 KB
    const int bn = blockIdx.x, bm = blockIdx.y, kz = blockIdx.z;
    const int tid = threadIdx.x, lane = tid & 63, wv = tid >> 6;
    const int wrow = (wv >> 1) * 64, wcol = (wv & 1) * 64;
    const int r15 = lane & 15, khi = lane >> 4;

    const u16* gA[2] = {A0, A1};
    const u16* gB[2] = {B0, B1};
    const int kg0 = kz * ksteps;

    auto stage = [&](int kg, int buf) {
        #pragma unroll
        for (int s = 0; s < 2; ++s) {
            const u16* g = gA[s] + ((size_t)(kg * rowsA + bm * 128 + wv * 32) * 32) + lane * 8;
            u16* l = &lds[buf][s * 4096 + wv * 1024 + lane * 8];
            GLL16(g, l);
            GLL16(g + 512, l + 512);
        }
        #pragma unroll
        for (int s = 0; s < 2; ++s) {
            const u16* g = gB[s] + ((size_t)(kg * rowsB + bn * 128 + wv * 32) * 32) + lane * 8;
            u16* l = &lds[buf][(2 + s) * 4096 + wv * 1024 + lane * 8];
            GLL16(g, l);
            GLL16(g + 512, l + 512);
        }
    };

    f32x4 acc[4][4];
    #pragma unroll
    for (int i = 0; i < 4; ++i)
        #pragma unroll
        for (int j = 0; j < 4; ++j) acc[i][j] = (f32x4){0.f, 0.f, 0.f, 0.f};

    // prologue: stage tile 0 into phase 0
    stage(kg0, 0);
    asm volatile("s_waitcnt vmcnt(0)" ::: "memory");
    __builtin_amdgcn_s_barrier();

    int cur = 0;
    for (int ks = 0; ks < ksteps; ++ks) {
        // ---- fragment ds_reads from lds[cur] (compiler inserts lgkm waits)
        f16x8 af[4][2], bf[4][2];
        #pragma unroll
        for (int i = 0; i < 4; ++i) {
            const int rowA = wrow + i * 16 + r15;
            const int offA = rowA * 64 + ((khi * 16) ^ (((rowA >> 1) & 3) << 4));
            const int rowB = wcol + i * 16 + r15;
            const int offB = rowB * 64 + ((khi * 16) ^ (((rowB >> 1) & 3) << 4));
            #pragma unroll
            for (int s = 0; s < 2; ++s) {
                af[i][s] = *(const f16x8*)((const char*)&lds[cur][s * 4096] + offA);
                bf[i][s] = *(const f16x8*)((const char*)&lds[cur][(2 + s) * 4096] + offB);
            }
        }
        // ---- issue next-tile staging; MFMAs below have no vmcnt dependence
        if (ks + 1 < ksteps) stage(kg0 + ks + 1, cur ^ 1);
        // ---- 4 split products: (a0+a1)(b0+b1), fp32 accumulate = exact sum
        #pragma unroll
        for (int p = 0; p < 4; ++p) {
            const int pa = p >> 1, pb = p & 1;
            #pragma unroll
            for (int i = 0; i < 4; ++i)
                #pragma unroll
                for (int j = 0; j < 4; ++j)
                    acc[i][j] = __builtin_amdgcn_mfma_f32_16x16x32_f16(
                        af[i][pa], bf[j][pb], acc[i][j], 0, 0, 0);
        }
        // ---- next tile staged + visible before anyone reads it
        asm volatile("s_waitcnt vmcnt(0)" ::: "memory");
        __builtin_amdgcn_s_barrier();
        cur ^= 1;
    }

    float* pt = part + (size_t)kz * ((size_t)N_SAMP * ldc);
    #pragma unroll
    for (int i = 0; i < 4; ++i) {
        const int row0 = bm * 128 + wrow + i * 16 + khi * 4;
        #pragma unroll
        for (int j = 0; j < 4; ++j) {
            const int col = bn * 128 + wcol + j * 16 + r15;
            #pragma unroll
            for (int q = 0; q < 4; ++q)
                pt[(size_t)(row0 + q) * ldc + col] = acc[i][j][q];
        }
    }
}

// ---------------------------------------------------------------------------
// Kernel 4: reduce fc1 split-K partials + bias + ReLU -> x fp32, and split2
// x into swizzled X0/X1 (rows=1024, K=1024) for the cls GEMM.
// ---------------------------------------------------------------------------
__global__ __launch_bounds__(256) void reduce_fc1(const float* __restrict__ part,
                                                  const float* __restrict__ bias,
                                                  float* __restrict__ x,
                                                  u16* __restrict__ x0,
                                                  u16* __restrict__ x1,
                                                  int nsplit) {
    const int i = blockIdx.x * 256 + threadIdx.x;     // float4 index, 262144 total
    const float4* p = reinterpret_cast<const float4*>(part);
    float4 s = p[i];
    for (int z = 1; z < nsplit; ++z) {
        const float4 t = p[(size_t)z * 262144 + i];
        s.x += t.x; s.y += t.y; s.z += t.z; s.w += t.w;
    }
    const float4 b = reinterpret_cast<const float4*>(bias)[i & 255];
    s.x = fmaxf(s.x + b.x, 0.f); s.y = fmaxf(s.y + b.y, 0.f);
    s.z = fmaxf(s.z + b.z, 0.f); s.w = fmaxf(s.w + b.w, 0.f);
    reinterpret_cast<float4*>(x)[i] = s;
    const int n = i >> 8, d0 = (i & 255) * 4;
    split2(s.x, x0, x1, split_idx_r(n, d0 + 0, N_SAMP));
    split2(s.y, x0, x1, split_idx_r(n, d0 + 1, N_SAMP));
    split2(s.z, x0, x1, split_idx_r(n, d0 + 2, N_SAMP));
    split2(s.w, x0, x1, split_idx_r(n, d0 + 3, N_SAMP));
}

// ---------------------------------------------------------------------------
// Kernel 5: fused decode + expert. Block per sample, 128 threads.
// Phase A: stage x[n] to LDS; reduce cls split-K partials + bias; sigmoid ->
// pose_cls; ballot -> ordinal labels (wave0 = pos, wave1 = orient) -> LDS.
// Phase B: wave0 computes pose[0..2] (pos expert), wave1 pose[3..6] (orient).
// ---------------------------------------------------------------------------
__global__ __launch_bounds__(128) void decode_expert(const float* __restrict__ part2,
                                                     const float* __restrict__ bp,
                                                     const float* __restrict__ bo,
                                                     const float* __restrict__ x,
                                                     const float* __restrict__ wpos,
                                                     const float* __restrict__ bpos,
                                                     const float* __restrict__ wori,
                                                     const float* __restrict__ bori,
                                                     float* __restrict__ pose_cls,
                                                     float* __restrict__ pose,
                                                     int nsplit) {
    const int n = blockIdx.x, t = threadIdx.x;
    __shared__ float xs[LATENT_D];
    __shared__ int esh[2];

    // stage x[n] (1024 floats, 2 float4 per thread)
    const float4* x4 = reinterpret_cast<const float4*>(x + (size_t)n * LATENT_D);
    float4* xs4 = reinterpret_cast<float4*>(xs);
    xs4[t] = x4[t];
    xs4[t + 128] = x4[t + 128];

    // decode
    float s = (t < 64) ? bp[t] : bo[t - 64];
    for (int z = 0; z < nsplit; ++z)
        s += part2[(size_t)z * (N_SAMP * 128) + (size_t)n * 128 + t];
    const float sig = 1.0f / (1.0f + expf(-s));
    const int head = t >> 6, c = t & 63;
    pose_cls[(size_t)n * (NCLS * 2) + c * 2 + head] = sig;

    const unsigned long long mask = __ballot(s > 0.0f);
    if (c == 0) {
        const unsigned long long inv = ~mask;
        const int run = inv ? __builtin_ctzll(inv) : 64;
        const int lab = run - 1;
        esh[head] = lab > 0 ? lab : 0;
    }
    __syncthreads();

    // expert: wave `head` handles its head's outputs
    const int e = esh[head];
    const int nk = head ? 4 : 3;
    for (int kk = 0; kk < nk; ++kk) {
        const float* wr = head ? wori + (size_t)(e * 4 + kk) * LATENT_D
                               : wpos + (size_t)(e * 3 + kk) * LATENT_D;
        const float bb = head ? bori[e * 4 + kk] : bpos[e * 3 + kk];
        const float4* w4 = reinterpret_cast<const float4*>(wr);
        float s2 = 0.f;
        #pragma unroll
        for (int i = 0; i < 4; ++i) {
            const int q = c + i * 64;
            const float4 a = w4[q];
            s2 += a.x * xs[q * 4] + a.y * xs[q * 4 + 1] + a.z * xs[q * 4 + 2] + a.w * xs[q * 4 + 3];
        }
        #pragma unroll
        for (int off = 32; off > 0; off >>= 1) s2 += __shfl_down(s2, off);
        if (c == 0) pose[(size_t)n * 7 + (head ? 3 + kk : kk)] = s2 + bb;
    }
}

// ---------------------------------------------------------------------------
extern "C" void kernel_launch(void* const* d_in, const int* in_sizes, int n_in,
                              void* d_out, int out_size, void* d_ws, size_t ws_size,
                              hipStream_t stream) {
    const float* feat   = (const float*)d_in[0];
    const float* fc1_w  = (const float*)d_in[1];
    const float* fc1_b  = (const float*)d_in[2];
    const float* cpw    = (const float*)d_in[3];
    const float* cpb    = (const float*)d_in[4];
    const float* cow    = (const float*)d_in[5];
    const float* cob    = (const float*)d_in[6];
    const float* rpw    = (const float*)d_in[7];
    const float* rpb    = (const float*)d_in[8];
    const float* row_   = (const float*)d_in[9];
    const float* rob    = (const float*)d_in[10];

    float* out = (float*)d_out;
    float* pose     = out;                          // [1024][7]
    float* pose_cls = out + (size_t)N_SAMP * 7;     // [1024][64][2]

    char* ws = (char*)d_ws;
    const size_t MB = (size_t)1 << 20;
    size_t off = 0;
    auto take = [&](size_t bytes) { char* p = ws + off; off += (bytes + 255) & ~(size_t)255; return p; };

    u16* A0 = (u16*)take(4 * MB);      // 64kg x 1024 x 32 x 2B
    u16* A1 = (u16*)take(4 * MB);
    u16* B0 = (u16*)take(4 * MB);
    u16* B1 = (u16*)take(4 * MB);
    u16* C0 = (u16*)take(256 * 1024);  // 32kg x 128 x 32 x 2B
    u16* C1 = (u16*)take(256 * 1024);
    u16* X0 = (u16*)take(2 * MB);      // 32kg x 1024 x 32 x 2B
    u16* X1 = (u16*)take(2 * MB);
    float* x = (float*)take(4 * MB);

    int nsplit = 8;
    while (nsplit > 1 && off + (size_t)nsplit * 4 * MB + 5 * MB > ws_size) nsplit >>= 1;
    float* part = (float*)take((size_t)nsplit * 4 * MB);
    int nsplit_c = 8;
    while (nsplit_c > 1 && off + (size_t)nsplit_c * 512 * 1024 > ws_size) nsplit_c >>= 1;
    float* part2 = (float*)take((size_t)nsplit_c * 512 * 1024);

    wsplit_kernel<<<8704, 256, 0, stream>>>(fc1_w, cpw, cow, B0, B1, C0, C1);
    pool_kernel<<<(N_SAMP * BD) / 256, 256, 0, stream>>>(feat, A0, A1);
    // fc1: M=1024, N=1024, K=2048
    split_mfma<<<dim3(8, 8, nsplit), 256, 0, stream>>>(
        A0, A1, B0, B1, part, 64 / nsplit, N_SAMP, LATENT_D, LATENT_D);
    reduce_fc1<<<1024, 256, 0, stream>>>(part, fc1_b, x, X0, X1, nsplit);
    // cls: M=1024, N=128, K=1024
    split_mfma<<<dim3(1, 8, nsplit_c), 256, 0, stream>>>(
        X0, X1, C0, C1, part2, 32 / nsplit_c, N_SAMP, 128, 128);
    decode_expert<<<N_SAMP, 128, 0, stream>>>(part2, cpb, cob, x, rpw, rpb, row_, rob,
                                              pose_cls, pose, nsplit_c);
}

// Round 5
// 136.188 us; speedup vs baseline: 2.2485x; 1.1339x over previous
//
#include <hip/hip_runtime.h>
#include <hip/hip_bf16.h>

#define N_SAMP   1024
#define BD       2048
#define LATENT_D 1024
#define NCLS     64
#define HW       49

typedef __attribute__((ext_vector_type(8))) _Float16 f16x8;
typedef __attribute__((ext_vector_type(4))) float f32x4;
typedef unsigned short u16;

// ---------------------------------------------------------------------------
// Split-fp16 tiled+swizzled layout (rounds 2-4, verified):
//   segment (kg = k>>5, row) = 32 ushorts (64 B) at ((kg*rows + row)*32),
//   byte within segment: c2 = (ke*2) ^ (((row>>1)&3)<<4).
// 128-row x 32-k tile = one contiguous 8 KB chunk; linear global_load_lds
// lands pre-swizzled for conflict-light ds_read_b128 (G21 source==read perm).
// fp16 2-way split: v = h0 + h1, rel err ~2^-22 -> fp32-grade GEMM, 4 MFMAs.
// ---------------------------------------------------------------------------
__device__ __forceinline__ size_t split_idx_r(int row, int k, int rows) {
    const int kg = k >> 5, ke = k & 31;
    const int c2 = (ke * 2) ^ (((row >> 1) & 3) << 4);
    return ((size_t)(kg * rows + row) * 32) + (c2 >> 1);
}

__device__ __forceinline__ void split2(float v, u16* p0, u16* p1, size_t idx) {
    _Float16 h0 = (_Float16)v;
    _Float16 h1 = (_Float16)(v - (float)h0);
    p0[idx] = *(u16*)&h0;
    p1[idx] = *(u16*)&h1;
}

#define GLL16(g, l) __builtin_amdgcn_global_load_lds( \
    (const __attribute__((address_space(1))) void*)(g), \
    (__attribute__((address_space(3))) void*)(l), 16, 0, 0)

// ---------------------------------------------------------------------------
// Kernel 1 (fused prep):
//  blocks [0, 8192):      avg-pool 7x7 -> split2 -> A0/A1 (rows=1024, K=2048).
//    Staging via global_load_lds (async, no VGPR round-trip): 49 x 1KB per
//    block. LDS sum at stride 49 floats = 2-way bank alias = free (m136).
//  blocks [8192, 16384):  fc1_w split -> B0/B1 (rows=1024, K=2048).
//  blocks [16384, 16896): cls weights [64 pos | 64 orient] -> C0/C1 (rows=128).
// ---------------------------------------------------------------------------
__global__ __launch_bounds__(256) void prep_kernel(const float* __restrict__ feat,
                                                   const float* __restrict__ W,
                                                   const float* __restrict__ Wp,
                                                   const float* __restrict__ Wo,
                                                   u16* __restrict__ a0,
                                                   u16* __restrict__ a1,
                                                   u16* __restrict__ b0,
                                                   u16* __restrict__ b1,
                                                   u16* __restrict__ c0,
                                                   u16* __restrict__ c1) {
    __shared__ float buf[256 * HW];                  // 50176 B (pool blocks only)
    const int b = blockIdx.x;
    const int tid = threadIdx.x;
    if (b < 8192) {
        const int lane = tid & 63, wv = tid >> 6;
        const float* src = feat + (size_t)b * (256 * HW);
        // 49 x 1KB async copies; wave wv takes chunks wv, wv+4, ...
        for (int c = wv; c < 49; c += 4)
            GLL16(src + c * 256 + lane * 4, (char*)buf + c * 1024 + lane * 16);
        asm volatile("s_waitcnt vmcnt(0)" ::: "memory");
        __syncthreads();
        const float* p = buf + tid * HW;
        float s = 0.f;
        #pragma unroll
        for (int k = 0; k < HW; ++k) s += p[k];
        const float v = s * (1.0f / 49.0f);
        const int n = b >> 3;
        const int d = (b & 7) * 256 + tid;
        split2(v, a0, a1, split_idx_r(n, d, N_SAMP));
    } else if (b < 16384) {
        const int b2 = b - 8192;
        const int row = b2 >> 3;
        const int d = (b2 & 7) * 256 + tid;
        split2(W[(size_t)row * BD + d], b0, b1, split_idx_r(row, d, LATENT_D));
    } else {
        const int b2 = b - 16384;
        const int row = b2 >> 2;                            // 0..127
        const int d = (b2 & 3) * 256 + tid;                 // 0..1023
        const float v = row < 64 ? Wp[(size_t)row * LATENT_D + d]
                                 : Wo[(size_t)(row - 64) * LATENT_D + d];
        split2(v, c0, c1, split_idx_r(row, d, 128));
    }
}

// ---------------------------------------------------------------------------
// Kernel 2: split-fp16 MFMA GEMM, 4 products, fp32-grade (verified round 4).
// Tile 128x128, BK=32, 4 waves x (64x64 quadrant of 4x4 16x16x32 frags).
// Double-buffered LDS; 2-phase prefetch (stage t+1 between ds_read and MFMA);
// one vmcnt(0)+barrier per K-step. Split-K via blockIdx.z.
// ---------------------------------------------------------------------------
__global__ __launch_bounds__(256, 2) void split_mfma(
    const u16* __restrict__ A0, const u16* __restrict__ A1,
    const u16* __restrict__ B0, const u16* __restrict__ B1,
    float* __restrict__ part, int ksteps, int rowsA, int rowsB, int ldc) {
    __shared__ u16 lds[2][4 * 4096];   // 2 phases x (A0|A1|B0|B1) x 8 KB
    const int bn = blockIdx.x, bm = blockIdx.y, kz = blockIdx.z;
    const int tid = threadIdx.x, lane = tid & 63, wv = tid >> 6;
    const int wrow = (wv >> 1) * 64, wcol = (wv & 1) * 64;
    const int r15 = lane & 15, khi = lane >> 4;

    const u16* gA[2] = {A0, A1};
    const u16* gB[2] = {B0, B1};
    const int kg0 = kz * ksteps;

    auto stage = [&](int kg, int buf) {
        #pragma unroll
        for (int s = 0; s < 2; ++s) {
            const u16* g = gA[s] + ((size_t)(kg * rowsA + bm * 128 + wv * 32) * 32) + lane * 8;
            u16* l = &lds[buf][s * 4096 + wv * 1024 + lane * 8];
            GLL16(g, l);
            GLL16(g + 512, l + 512);
        }
        #pragma unroll
        for (int s = 0; s < 2; ++s) {
            const u16* g = gB[s] + ((size_t)(kg * rowsB + bn * 128 + wv * 32) * 32) + lane * 8;
            u16* l = &lds[buf][(2 + s) * 4096 + wv * 1024 + lane * 8];
            GLL16(g, l);
            GLL16(g + 512, l + 512);
        }
    };

    f32x4 acc[4][4];
    #pragma unroll
    for (int i = 0; i < 4; ++i)
        #pragma unroll
        for (int j = 0; j < 4; ++j) acc[i][j] = (f32x4){0.f, 0.f, 0.f, 0.f};

    stage(kg0, 0);
    asm volatile("s_waitcnt vmcnt(0)" ::: "memory");
    __builtin_amdgcn_s_barrier();

    int cur = 0;
    for (int ks = 0; ks < ksteps; ++ks) {
        f16x8 af[4][2], bf[4][2];
        #pragma unroll
        for (int i = 0; i < 4; ++i) {
            const int rowA = wrow + i * 16 + r15;
            const int offA = rowA * 64 + ((khi * 16) ^ (((rowA >> 1) & 3) << 4));
            const int rowB = wcol + i * 16 + r15;
            const int offB = rowB * 64 + ((khi * 16) ^ (((rowB >> 1) & 3) << 4));
            #pragma unroll
            for (int s = 0; s < 2; ++s) {
                af[i][s] = *(const f16x8*)((const char*)&lds[cur][s * 4096] + offA);
                bf[i][s] = *(const f16x8*)((const char*)&lds[cur][(2 + s) * 4096] + offB);
            }
        }
        if (ks + 1 < ksteps) stage(kg0 + ks + 1, cur ^ 1);
        #pragma unroll
        for (int p = 0; p < 4; ++p) {
            const int pa = p >> 1, pb = p & 1;
            #pragma unroll
            for (int i = 0; i < 4; ++i)
                #pragma unroll
                for (int j = 0; j < 4; ++j)
                    acc[i][j] = __builtin_amdgcn_mfma_f32_16x16x32_f16(
                        af[i][pa], bf[j][pb], acc[i][j], 0, 0, 0);
        }
        asm volatile("s_waitcnt vmcnt(0)" ::: "memory");
        __builtin_amdgcn_s_barrier();
        cur ^= 1;
    }

    float* pt = part + (size_t)kz * ((size_t)N_SAMP * ldc);
    #pragma unroll
    for (int i = 0; i < 4; ++i) {
        const int row0 = bm * 128 + wrow + i * 16 + khi * 4;
        #pragma unroll
        for (int j = 0; j < 4; ++j) {
            const int col = bn * 128 + wcol + j * 16 + r15;
            #pragma unroll
            for (int q = 0; q < 4; ++q)
                pt[(size_t)(row0 + q) * ldc + col] = acc[i][j][q];
        }
    }
}

// ---------------------------------------------------------------------------
// Kernel 3: reduce fc1 split-K partials + bias + ReLU -> x fp32, and split2
// x into swizzled X0/X1 (rows=1024, K=1024) for the cls GEMM.
// ---------------------------------------------------------------------------
__global__ __launch_bounds__(256) void reduce_fc1(const float* __restrict__ part,
                                                  const float* __restrict__ bias,
                                                  float* __restrict__ x,
                                                  u16* __restrict__ x0,
                                                  u16* __restrict__ x1,
                                                  int nsplit) {
    const int i = blockIdx.x * 256 + threadIdx.x;     // float4 index, 262144 total
    const float4* p = reinterpret_cast<const float4*>(part);
    float4 s = p[i];
    for (int z = 1; z < nsplit; ++z) {
        const float4 t = p[(size_t)z * 262144 + i];
        s.x += t.x; s.y += t.y; s.z += t.z; s.w += t.w;
    }
    const float4 b = reinterpret_cast<const float4*>(bias)[i & 255];
    s.x = fmaxf(s.x + b.x, 0.f); s.y = fmaxf(s.y + b.y, 0.f);
    s.z = fmaxf(s.z + b.z, 0.f); s.w = fmaxf(s.w + b.w, 0.f);
    reinterpret_cast<float4*>(x)[i] = s;
    const int n = i >> 8, d0 = (i & 255) * 4;
    split2(s.x, x0, x1, split_idx_r(n, d0 + 0, N_SAMP));
    split2(s.y, x0, x1, split_idx_r(n, d0 + 1, N_SAMP));
    split2(s.z, x0, x1, split_idx_r(n, d0 + 2, N_SAMP));
    split2(s.w, x0, x1, split_idx_r(n, d0 + 3, N_SAMP));
}

// ---------------------------------------------------------------------------
// Kernel 4: fused decode + expert (verified round 4). Block per sample.
// ---------------------------------------------------------------------------
__global__ __launch_bounds__(128) void decode_expert(const float* __restrict__ part2,
                                                     const float* __restrict__ bp,
                                                     const float* __restrict__ bo,
                                                     const float* __restrict__ x,
                                                     const float* __restrict__ wpos,
                                                     const float* __restrict__ bpos,
                                                     const float* __restrict__ wori,
                                                     const float* __restrict__ bori,
                                                     float* __restrict__ pose_cls,
                                                     float* __restrict__ pose,
                                                     int nsplit) {
    const int n = blockIdx.x, t = threadIdx.x;
    __shared__ float xs[LATENT_D];
    __shared__ int esh[2];

    const float4* x4 = reinterpret_cast<const float4*>(x + (size_t)n * LATENT_D);
    float4* xs4 = reinterpret_cast<float4*>(xs);
    xs4[t] = x4[t];
    xs4[t + 128] = x4[t + 128];

    float s = (t < 64) ? bp[t] : bo[t - 64];
    for (int z = 0; z < nsplit; ++z)
        s += part2[(size_t)z * (N_SAMP * 128) + (size_t)n * 128 + t];
    const float sig = 1.0f / (1.0f + expf(-s));
    const int head = t >> 6, c = t & 63;
    pose_cls[(size_t)n * (NCLS * 2) + c * 2 + head] = sig;

    const unsigned long long mask = __ballot(s > 0.0f);
    if (c == 0) {
        const unsigned long long inv = ~mask;
        const int run = inv ? __builtin_ctzll(inv) : 64;
        const int lab = run - 1;
        esh[head] = lab > 0 ? lab : 0;
    }
    __syncthreads();

    const int e = esh[head];
    const int nk = head ? 4 : 3;
    for (int kk = 0; kk < nk; ++kk) {
        const float* wr = head ? wori + (size_t)(e * 4 + kk) * LATENT_D
                               : wpos + (size_t)(e * 3 + kk) * LATENT_D;
        const float bb = head ? bori[e * 4 + kk] : bpos[e * 3 + kk];
        const float4* w4 = reinterpret_cast<const float4*>(wr);
        float s2 = 0.f;
        #pragma unroll
        for (int i = 0; i < 4; ++i) {
            const int q = c + i * 64;
            const float4 a = w4[q];
            s2 += a.x * xs[q * 4] + a.y * xs[q * 4 + 1] + a.z * xs[q * 4 + 2] + a.w * xs[q * 4 + 3];
        }
        #pragma unroll
        for (int off = 32; off > 0; off >>= 1) s2 += __shfl_down(s2, off);
        if (c == 0) pose[(size_t)n * 7 + (head ? 3 + kk : kk)] = s2 + bb;
    }
}

// ---------------------------------------------------------------------------
extern "C" void kernel_launch(void* const* d_in, const int* in_sizes, int n_in,
                              void* d_out, int out_size, void* d_ws, size_t ws_size,
                              hipStream_t stream) {
    const float* feat   = (const float*)d_in[0];
    const float* fc1_w  = (const float*)d_in[1];
    const float* fc1_b  = (const float*)d_in[2];
    const float* cpw    = (const float*)d_in[3];
    const float* cpb    = (const float*)d_in[4];
    const float* cow    = (const float*)d_in[5];
    const float* cob    = (const float*)d_in[6];
    const float* rpw    = (const float*)d_in[7];
    const float* rpb    = (const float*)d_in[8];
    const float* row_   = (const float*)d_in[9];
    const float* rob    = (const float*)d_in[10];

    float* out = (float*)d_out;
    float* pose     = out;                          // [1024][7]
    float* pose_cls = out + (size_t)N_SAMP * 7;     // [1024][64][2]

    char* ws = (char*)d_ws;
    const size_t MB = (size_t)1 << 20;
    size_t off = 0;
    auto take = [&](size_t bytes) { char* p = ws + off; off += (bytes + 255) & ~(size_t)255; return p; };

    u16* A0 = (u16*)take(4 * MB);      // 64kg x 1024 x 32 x 2B
    u16* A1 = (u16*)take(4 * MB);
    u16* B0 = (u16*)take(4 * MB);
    u16* B1 = (u16*)take(4 * MB);
    u16* C0 = (u16*)take(256 * 1024);  // 32kg x 128 x 32 x 2B
    u16* C1 = (u16*)take(256 * 1024);
    u16* X0 = (u16*)take(2 * MB);      // 32kg x 1024 x 32 x 2B
    u16* X1 = (u16*)take(2 * MB);
    float* x = (float*)take(4 * MB);

    int nsplit = 8;
    while (nsplit > 1 && off + (size_t)nsplit * 4 * MB + 3 * MB > ws_size) nsplit >>= 1;
    float* part = (float*)take((size_t)nsplit * 4 * MB);
    int nsplit_c = 4;
    while (nsplit_c > 1 && off + (size_t)nsplit_c * 512 * 1024 > ws_size) nsplit_c >>= 1;
    float* part2 = (float*)take((size_t)nsplit_c * 512 * 1024);

    // 1. fused prep: pool->A splits, fc1_w->B splits, cls->C splits
    prep_kernel<<<16896, 256, 0, stream>>>(feat, fc1_w, cpw, cow,
                                           A0, A1, B0, B1, C0, C1);
    // 2. fc1: M=1024, N=1024, K=2048
    split_mfma<<<dim3(8, 8, nsplit), 256, 0, stream>>>(
        A0, A1, B0, B1, part, 64 / nsplit, N_SAMP, LATENT_D, LATENT_D);
    // 3. reduce + bias + relu + x-split
    reduce_fc1<<<1024, 256, 0, stream>>>(part, fc1_b, x, X0, X1, nsplit);
    // 4. cls: M=1024, N=128, K=1024
    split_mfma<<<dim3(1, 8, nsplit_c), 256, 0, stream>>>(
        X0, X1, C0, C1, part2, 32 / nsplit_c, N_SAMP, 128, 128);
    // 5. decode + expert
    decode_expert<<<N_SAMP, 128, 0, stream>>>(part2, cpb, cob, x, rpw, rpb, row_, rob,
                                              pose_cls, pose, nsplit_c);
}

// Round 6
// 132.960 us; speedup vs baseline: 2.3031x; 1.0243x over previous
//
#include <hip/hip_runtime.h>
#include <hip/hip_bf16.h>

#define N_SAMP   1024
#define BD       2048
#define LATENT_D 1024
#define NCLS     64
#define HW       49

typedef __attribute__((ext_vector_type(8))) _Float16 f16x8;
typedef __attribute__((ext_vector_type(4))) float f32x4;
typedef unsigned short u16;

// ---------------------------------------------------------------------------
// Split-fp16 tiled+swizzled layout (rounds 2-5, verified):
//   segment (kg = k>>5, row) = 32 ushorts (64 B) at ((kg*rows + row)*32),
//   byte within segment: c2 = (ke*2) ^ (((row>>1)&3)<<4).
// 128-row x 32-k tile = one contiguous 8 KB chunk; linear global_load_lds
// lands pre-swizzled for conflict-light ds_read_b128 (G21 source==read perm).
// fp16 2-way split: v = h0 + h1, rel err ~2^-22. GEMM uses 3 products
// (a0b0 + a0b1 + a1b0); dropped a1b1 <= 2^-22 rel -> ~5e-8 logit error,
// below fp32's own reorder noise. fp32-grade.
// ---------------------------------------------------------------------------
__device__ __forceinline__ size_t split_idx_r(int row, int k, int rows) {
    const int kg = k >> 5, ke = k & 31;
    const int c2 = (ke * 2) ^ (((row >> 1) & 3) << 4);
    return ((size_t)(kg * rows + row) * 32) + (c2 >> 1);
}

__device__ __forceinline__ void split2(float v, u16* p0, u16* p1, size_t idx) {
    _Float16 h0 = (_Float16)v;
    _Float16 h1 = (_Float16)(v - (float)h0);
    p0[idx] = *(u16*)&h0;
    p1[idx] = *(u16*)&h1;
}

#define GLL16(g, l) __builtin_amdgcn_global_load_lds( \
    (const __attribute__((address_space(1))) void*)(g), \
    (__attribute__((address_space(3))) void*)(l), 16, 0, 0)

// ---------------------------------------------------------------------------
// Kernel 1 (fused prep):
//  blocks [0, 8192):      avg-pool 7x7 -> split2 -> A0/A1 (rows=1024, K=2048).
//    Staging via global_load_lds (async, no VGPR round-trip): 49 x 1KB per
//    block. LDS sum at stride 49 floats = 2-way bank alias = free (m136).
//  blocks [8192, 16384):  fc1_w split -> B0/B1 (rows=1024, K=2048).
//  blocks [16384, 16896): cls weights [64 pos | 64 orient] -> C0/C1 (rows=128).
// ---------------------------------------------------------------------------
__global__ __launch_bounds__(256) void prep_kernel(const float* __restrict__ feat,
                                                   const float* __restrict__ W,
                                                   const float* __restrict__ Wp,
                                                   const float* __restrict__ Wo,
                                                   u16* __restrict__ a0,
                                                   u16* __restrict__ a1,
                                                   u16* __restrict__ b0,
                                                   u16* __restrict__ b1,
                                                   u16* __restrict__ c0,
                                                   u16* __restrict__ c1) {
    __shared__ float buf[256 * HW];                  // 50176 B (pool blocks only)
    const int b = blockIdx.x;
    const int tid = threadIdx.x;
    if (b < 8192) {
        const int lane = tid & 63, wv = tid >> 6;
        const float* src = feat + (size_t)b * (256 * HW);
        for (int c = wv; c < 49; c += 4)
            GLL16(src + c * 256 + lane * 4, (char*)buf + c * 1024 + lane * 16);
        asm volatile("s_waitcnt vmcnt(0)" ::: "memory");
        __syncthreads();
        const float* p = buf + tid * HW;
        float s = 0.f;
        #pragma unroll
        for (int k = 0; k < HW; ++k) s += p[k];
        const float v = s * (1.0f / 49.0f);
        const int n = b >> 3;
        const int d = (b & 7) * 256 + tid;
        split2(v, a0, a1, split_idx_r(n, d, N_SAMP));
    } else if (b < 16384) {
        const int b2 = b - 8192;
        const int row = b2 >> 3;
        const int d = (b2 & 7) * 256 + tid;
        split2(W[(size_t)row * BD + d], b0, b1, split_idx_r(row, d, LATENT_D));
    } else {
        const int b2 = b - 16384;
        const int row = b2 >> 2;                            // 0..127
        const int d = (b2 & 3) * 256 + tid;                 // 0..1023
        const float v = row < 64 ? Wp[(size_t)row * LATENT_D + d]
                                 : Wo[(size_t)(row - 64) * LATENT_D + d];
        split2(v, c0, c1, split_idx_r(row, d, 128));
    }
}

// ---------------------------------------------------------------------------
// Kernel 2: split-fp16 MFMA GEMM, 3 products, fp32-grade (rounds 4-5 + this).
// Tile 128x128, BK=32, 4 waves x (64x64 quadrant of 4x4 16x16x32 frags).
// Double-buffered LDS; 2-phase prefetch; one vmcnt(0)+barrier per K-step.
// Split-K via blockIdx.z. XCD-bijective block swizzle (T1): each XCD gets a
// contiguous chunk of the flat grid -> its kz-slice's A+B slabs (~2 MB) stay
// L2-resident (4 MB/XCD). Requires nwg % 8 == 0 (512 and 32: both ok).
// ---------------------------------------------------------------------------
__global__ __launch_bounds__(256, 2) void split_mfma(
    const u16* __restrict__ A0, const u16* __restrict__ A1,
    const u16* __restrict__ B0, const u16* __restrict__ B1,
    float* __restrict__ part, int ksteps, int rowsA, int rowsB, int ldc) {
    __shared__ u16 lds[2][4 * 4096];   // 2 phases x (A0|A1|B0|B1) x 8 KB
    // ---- XCD swizzle: flat id -> contiguous chunk per XCD, bn-fastest decode
    const int nwg = gridDim.x * gridDim.y * gridDim.z;
    const int flat = blockIdx.x + gridDim.x * (blockIdx.y + gridDim.y * blockIdx.z);
    const int chunk = nwg >> 3;                   // nwg % 8 == 0 by construction
    const int swz = (flat & 7) * chunk + (flat >> 3);
    const int bn = swz % gridDim.x;
    const int rest = swz / gridDim.x;
    const int bm = rest % gridDim.y;
    const int kz = rest / gridDim.y;

    const int tid = threadIdx.x, lane = tid & 63, wv = tid >> 6;
    const int wrow = (wv >> 1) * 64, wcol = (wv & 1) * 64;
    const int r15 = lane & 15, khi = lane >> 4;

    const u16* gA[2] = {A0, A1};
    const u16* gB[2] = {B0, B1};
    const int kg0 = kz * ksteps;

    auto stage = [&](int kg, int buf) {
        #pragma unroll
        for (int s = 0; s < 2; ++s) {
            const u16* g = gA[s] + ((size_t)(kg * rowsA + bm * 128 + wv * 32) * 32) + lane * 8;
            u16* l = &lds[buf][s * 4096 + wv * 1024 + lane * 8];
            GLL16(g, l);
            GLL16(g + 512, l + 512);
        }
        #pragma unroll
        for (int s = 0; s < 2; ++s) {
            const u16* g = gB[s] + ((size_t)(kg * rowsB + bn * 128 + wv * 32) * 32) + lane * 8;
            u16* l = &lds[buf][(2 + s) * 4096 + wv * 1024 + lane * 8];
            GLL16(g, l);
            GLL16(g + 512, l + 512);
        }
    };

    f32x4 acc[4][4];
    #pragma unroll
    for (int i = 0; i < 4; ++i)
        #pragma unroll
        for (int j = 0; j < 4; ++j) acc[i][j] = (f32x4){0.f, 0.f, 0.f, 0.f};

    stage(kg0, 0);
    asm volatile("s_waitcnt vmcnt(0)" ::: "memory");
    __builtin_amdgcn_s_barrier();

    int cur = 0;
    for (int ks = 0; ks < ksteps; ++ks) {
        f16x8 af[4][2], bf[4][2];
        #pragma unroll
        for (int i = 0; i < 4; ++i) {
            const int rowA = wrow + i * 16 + r15;
            const int offA = rowA * 64 + ((khi * 16) ^ (((rowA >> 1) & 3) << 4));
            const int rowB = wcol + i * 16 + r15;
            const int offB = rowB * 64 + ((khi * 16) ^ (((rowB >> 1) & 3) << 4));
            #pragma unroll
            for (int s = 0; s < 2; ++s) {
                af[i][s] = *(const f16x8*)((const char*)&lds[cur][s * 4096] + offA);
                bf[i][s] = *(const f16x8*)((const char*)&lds[cur][(2 + s) * 4096] + offB);
            }
        }
        if (ks + 1 < ksteps) stage(kg0 + ks + 1, cur ^ 1);
        // 3 products: a0b0, a0b1, a1b0 (a1b1 dropped, <= 2^-22 rel)
        #pragma unroll
        for (int p = 0; p < 3; ++p) {
            const int pa = (p == 2) ? 1 : 0;
            const int pb = (p == 1) ? 1 : 0;
            #pragma unroll
            for (int i = 0; i < 4; ++i)
                #pragma unroll
                for (int j = 0; j < 4; ++j)
                    acc[i][j] = __builtin_amdgcn_mfma_f32_16x16x32_f16(
                        af[i][pa], bf[j][pb], acc[i][j], 0, 0, 0);
        }
        asm volatile("s_waitcnt vmcnt(0)" ::: "memory");
        __builtin_amdgcn_s_barrier();
        cur ^= 1;
    }

    float* pt = part + (size_t)kz * ((size_t)N_SAMP * ldc);
    #pragma unroll
    for (int i = 0; i < 4; ++i) {
        const int row0 = bm * 128 + wrow + i * 16 + khi * 4;
        #pragma unroll
        for (int j = 0; j < 4; ++j) {
            const int col = bn * 128 + wcol + j * 16 + r15;
            #pragma unroll
            for (int q = 0; q < 4; ++q)
                pt[(size_t)(row0 + q) * ldc + col] = acc[i][j][q];
        }
    }
}

// ---------------------------------------------------------------------------
// Kernel 3: reduce fc1 split-K partials + bias + ReLU -> x fp32, and split2
// x into swizzled X0/X1 (rows=1024, K=1024) for the cls GEMM.
// ---------------------------------------------------------------------------
__global__ __launch_bounds__(256) void reduce_fc1(const float* __restrict__ part,
                                                  const float* __restrict__ bias,
                                                  float* __restrict__ x,
                                                  u16* __restrict__ x0,
                                                  u16* __restrict__ x1,
                                                  int nsplit) {
    const int i = blockIdx.x * 256 + threadIdx.x;     // float4 index, 262144 total
    const float4* p = reinterpret_cast<const float4*>(part);
    float4 s = p[i];
    for (int z = 1; z < nsplit; ++z) {
        const float4 t = p[(size_t)z * 262144 + i];
        s.x += t.x; s.y += t.y; s.z += t.z; s.w += t.w;
    }
    const float4 b = reinterpret_cast<const float4*>(bias)[i & 255];
    s.x = fmaxf(s.x + b.x, 0.f); s.y = fmaxf(s.y + b.y, 0.f);
    s.z = fmaxf(s.z + b.z, 0.f); s.w = fmaxf(s.w + b.w, 0.f);
    reinterpret_cast<float4*>(x)[i] = s;
    const int n = i >> 8, d0 = (i & 255) * 4;
    split2(s.x, x0, x1, split_idx_r(n, d0 + 0, N_SAMP));
    split2(s.y, x0, x1, split_idx_r(n, d0 + 1, N_SAMP));
    split2(s.z, x0, x1, split_idx_r(n, d0 + 2, N_SAMP));
    split2(s.w, x0, x1, split_idx_r(n, d0 + 3, N_SAMP));
}

// ---------------------------------------------------------------------------
// Kernel 4: fused decode + expert (verified rounds 4-5). Block per sample.
// ---------------------------------------------------------------------------
__global__ __launch_bounds__(128) void decode_expert(const float* __restrict__ part2,
                                                     const float* __restrict__ bp,
                                                     const float* __restrict__ bo,
                                                     const float* __restrict__ x,
                                                     const float* __restrict__ wpos,
                                                     const float* __restrict__ bpos,
                                                     const float* __restrict__ wori,
                                                     const float* __restrict__ bori,
                                                     float* __restrict__ pose_cls,
                                                     float* __restrict__ pose,
                                                     int nsplit) {
    const int n = blockIdx.x, t = threadIdx.x;
    __shared__ float xs[LATENT_D];
    __shared__ int esh[2];

    const float4* x4 = reinterpret_cast<const float4*>(x + (size_t)n * LATENT_D);
    float4* xs4 = reinterpret_cast<float4*>(xs);
    xs4[t] = x4[t];
    xs4[t + 128] = x4[t + 128];

    float s = (t < 64) ? bp[t] : bo[t - 64];
    for (int z = 0; z < nsplit; ++z)
        s += part2[(size_t)z * (N_SAMP * 128) + (size_t)n * 128 + t];
    const float sig = 1.0f / (1.0f + expf(-s));
    const int head = t >> 6, c = t & 63;
    pose_cls[(size_t)n * (NCLS * 2) + c * 2 + head] = sig;

    const unsigned long long mask = __ballot(s > 0.0f);
    if (c == 0) {
        const unsigned long long inv = ~mask;
        const int run = inv ? __builtin_ctzll(inv) : 64;
        const int lab = run - 1;
        esh[head] = lab > 0 ? lab : 0;
    }
    __syncthreads();

    const int e = esh[head];
    const int nk = head ? 4 : 3;
    for (int kk = 0; kk < nk; ++kk) {
        const float* wr = head ? wori + (size_t)(e * 4 + kk) * LATENT_D
                               : wpos + (size_t)(e * 3 + kk) * LATENT_D;
        const float bb = head ? bori[e * 4 + kk] : bpos[e * 3 + kk];
        const float4* w4 = reinterpret_cast<const float4*>(wr);
        float s2 = 0.f;
        #pragma unroll
        for (int i = 0; i < 4; ++i) {
            const int q = c + i * 64;
            const float4 a = w4[q];
            s2 += a.x * xs[q * 4] + a.y * xs[q * 4 + 1] + a.z * xs[q * 4 + 2] + a.w * xs[q * 4 + 3];
        }
        #pragma unroll
        for (int off = 32; off > 0; off >>= 1) s2 += __shfl_down(s2, off);
        if (c == 0) pose[(size_t)n * 7 + (head ? 3 + kk : kk)] = s2 + bb;
    }
}

// ---------------------------------------------------------------------------
extern "C" void kernel_launch(void* const* d_in, const int* in_sizes, int n_in,
                              void* d_out, int out_size, void* d_ws, size_t ws_size,
                              hipStream_t stream) {
    const float* feat   = (const float*)d_in[0];
    const float* fc1_w  = (const float*)d_in[1];
    const float* fc1_b  = (const float*)d_in[2];
    const float* cpw    = (const float*)d_in[3];
    const float* cpb    = (const float*)d_in[4];
    const float* cow    = (const float*)d_in[5];
    const float* cob    = (const float*)d_in[6];
    const float* rpw    = (const float*)d_in[7];
    const float* rpb    = (const float*)d_in[8];
    const float* row_   = (const float*)d_in[9];
    const float* rob    = (const float*)d_in[10];

    float* out = (float*)d_out;
    float* pose     = out;                          // [1024][7]
    float* pose_cls = out + (size_t)N_SAMP * 7;     // [1024][64][2]

    char* ws = (char*)d_ws;
    const size_t MB = (size_t)1 << 20;
    size_t off = 0;
    auto take = [&](size_t bytes) { char* p = ws + off; off += (bytes + 255) & ~(size_t)255; return p; };

    u16* A0 = (u16*)take(4 * MB);      // 64kg x 1024 x 32 x 2B
    u16* A1 = (u16*)take(4 * MB);
    u16* B0 = (u16*)take(4 * MB);
    u16* B1 = (u16*)take(4 * MB);
    u16* C0 = (u16*)take(256 * 1024);  // 32kg x 128 x 32 x 2B
    u16* C1 = (u16*)take(256 * 1024);
    u16* X0 = (u16*)take(2 * MB);      // 32kg x 1024 x 32 x 2B
    u16* X1 = (u16*)take(2 * MB);
    float* x = (float*)take(4 * MB);

    int nsplit = 8;
    while (nsplit > 1 && off + (size_t)nsplit * 4 * MB + 3 * MB > ws_size) nsplit >>= 1;
    float* part = (float*)take((size_t)nsplit * 4 * MB);
    int nsplit_c = 4;
    while (nsplit_c > 1 && off + (size_t)nsplit_c * 512 * 1024 > ws_size) nsplit_c >>= 1;
    float* part2 = (float*)take((size_t)nsplit_c * 512 * 1024);

    // 1. fused prep: pool->A splits, fc1_w->B splits, cls->C splits
    prep_kernel<<<16896, 256, 0, stream>>>(feat, fc1_w, cpw, cow,
                                           A0, A1, B0, B1, C0, C1);
    // 2. fc1: M=1024, N=1024, K=2048  (512 blocks, %8==0 for XCD swizzle)
    split_mfma<<<dim3(8, 8, nsplit), 256, 0, stream>>>(
        A0, A1, B0, B1, part, 64 / nsplit, N_SAMP, LATENT_D, LATENT_D);
    // 3. reduce + bias + relu + x-split
    reduce_fc1<<<1024, 256, 0, stream>>>(part, fc1_b, x, X0, X1, nsplit);
    // 4. cls: M=1024, N=128, K=1024  (32 blocks, %8==0)
    split_mfma<<<dim3(1, 8, nsplit_c), 256, 0, stream>>>(
        X0, X1, C0, C1, part2, 32 / nsplit_c, N_SAMP, 128, 128);
    // 5. decode + expert
    decode_expert<<<N_SAMP, 128, 0, stream>>>(part2, cpb, cob, x, rpw, rpb, row_, rob,
                                              pose_cls, pose, nsplit_c);
}

// Round 7
// 128.600 us; speedup vs baseline: 2.3812x; 1.0339x over previous
//
#include <hip/hip_runtime.h>
#include <hip/hip_bf16.h>

#define N_SAMP   1024
#define BD       2048
#define LATENT_D 1024
#define NCLS     64
#define HW       49

typedef __attribute__((ext_vector_type(8))) _Float16 f16x8;
typedef __attribute__((ext_vector_type(4))) float f32x4;
typedef unsigned short u16;

// ---------------------------------------------------------------------------
// Split-fp16 tiled+swizzled layout (rounds 2-6, verified):
//   segment (kg = k>>5, row) = 32 ushorts (64 B) at ((kg*rows + row)*32),
//   byte within segment: c2 = (ke*2) ^ (((row>>1)&3)<<4).
// 128/64-row x 32-k tiles are contiguous chunks; linear global_load_lds lands
// pre-swizzled for conflict-light ds_read_b128 (G21 source==read perm).
// Local-row swizzle == global-row swizzle because tile row offsets (64/128)
// are multiples of 8 in the (row>>1)&3 window.
// fp16 2-way split, 3 products (a0b0+a0b1+a1b0): dropped a1b1 <= 2^-22 rel
// -> ~5e-8 logit error, below fp32's own reorder noise. fp32-grade.
// ---------------------------------------------------------------------------
__device__ __forceinline__ size_t split_idx_r(int row, int k, int rows) {
    const int kg = k >> 5, ke = k & 31;
    const int c2 = (ke * 2) ^ (((row >> 1) & 3) << 4);
    return ((size_t)(kg * rows + row) * 32) + (c2 >> 1);
}

__device__ __forceinline__ void split2(float v, u16* p0, u16* p1, size_t idx) {
    _Float16 h0 = (_Float16)v;
    _Float16 h1 = (_Float16)(v - (float)h0);
    p0[idx] = *(u16*)&h0;
    p1[idx] = *(u16*)&h1;
}

#define GLL16(g, l) __builtin_amdgcn_global_load_lds( \
    (const __attribute__((address_space(1))) void*)(g), \
    (__attribute__((address_space(3))) void*)(l), 16, 0, 0)

// ---------------------------------------------------------------------------
// Kernel 1 (fused prep):
//  blocks [0, 8192):      avg-pool 7x7 -> split2 -> A0/A1 (rows=1024, K=2048).
//    global_load_lds staging (async, no VGPR round-trip), stride-49 LDS sum
//    = 2-way bank alias = free (m136).
//  blocks [8192, 16384):  fc1_w split -> B0/B1 (rows=1024, K=2048).
//  blocks [16384, 16896): cls weights [64 pos | 64 orient] -> C0/C1 (rows=128).
// ---------------------------------------------------------------------------
__global__ __launch_bounds__(256) void prep_kernel(const float* __restrict__ feat,
                                                   const float* __restrict__ W,
                                                   const float* __restrict__ Wp,
                                                   const float* __restrict__ Wo,
                                                   u16* __restrict__ a0,
                                                   u16* __restrict__ a1,
                                                   u16* __restrict__ b0,
                                                   u16* __restrict__ b1,
                                                   u16* __restrict__ c0,
                                                   u16* __restrict__ c1) {
    __shared__ float buf[256 * HW];                  // 50176 B (pool blocks only)
    const int b = blockIdx.x;
    const int tid = threadIdx.x;
    if (b < 8192) {
        const int lane = tid & 63, wv = tid >> 6;
        const float* src = feat + (size_t)b * (256 * HW);
        for (int c = wv; c < 49; c += 4)
            GLL16(src + c * 256 + lane * 4, (char*)buf + c * 1024 + lane * 16);
        asm volatile("s_waitcnt vmcnt(0)" ::: "memory");
        __syncthreads();
        const float* p = buf + tid * HW;
        float s = 0.f;
        #pragma unroll
        for (int k = 0; k < HW; ++k) s += p[k];
        const float v = s * (1.0f / 49.0f);
        const int n = b >> 3;
        const int d = (b & 7) * 256 + tid;
        split2(v, a0, a1, split_idx_r(n, d, N_SAMP));
    } else if (b < 16384) {
        const int b2 = b - 8192;
        const int row = b2 >> 3;
        const int d = (b2 & 7) * 256 + tid;
        split2(W[(size_t)row * BD + d], b0, b1, split_idx_r(row, d, LATENT_D));
    } else {
        const int b2 = b - 16384;
        const int row = b2 >> 2;                            // 0..127
        const int d = (b2 & 3) * 256 + tid;                 // 0..1023
        const float v = row < 64 ? Wp[(size_t)row * LATENT_D + d]
                                 : Wo[(size_t)(row - 64) * LATENT_D + d];
        split2(v, c0, c1, split_idx_r(row, d, 128));
    }
}

// ---------------------------------------------------------------------------
// Kernel 2: fc1 split-fp16 MFMA GEMM, 3 products (verified rounds 4-6).
// Tile 128x128, BK=32, 4 waves x (64x64 quadrant of 4x4 16x16x32 frags).
// Double-buffered LDS; stage(t+1) issued right after barrier, BEFORE the
// ds_reads of tile t (T14-lite: staging latency hides under ds_read+MFMA).
// One vmcnt(0)+barrier per K-step. XCD-bijective swizzle (nwg=512, %8==0):
// XCD x handles exactly kz=x -> its A+B slab (2 MB) stays L2-resident.
// ---------------------------------------------------------------------------
__global__ __launch_bounds__(256, 2) void split_mfma(
    const u16* __restrict__ A0, const u16* __restrict__ A1,
    const u16* __restrict__ B0, const u16* __restrict__ B1,
    float* __restrict__ part, int ksteps, int rowsA, int rowsB, int ldc) {
    __shared__ u16 lds[2][4 * 4096];   // 2 phases x (A0|A1|B0|B1) x 8 KB
    const int nwg = gridDim.x * gridDim.y * gridDim.z;
    const int flat = blockIdx.x + gridDim.x * (blockIdx.y + gridDim.y * blockIdx.z);
    const int chunk = nwg >> 3;
    const int swz = (flat & 7) * chunk + (flat >> 3);
    const int bn = swz % gridDim.x;
    const int rest = swz / gridDim.x;
    const int bm = rest % gridDim.y;
    const int kz = rest / gridDim.y;

    const int tid = threadIdx.x, lane = tid & 63, wv = tid >> 6;
    const int wrow = (wv >> 1) * 64, wcol = (wv & 1) * 64;
    const int r15 = lane & 15, khi = lane >> 4;

    const u16* gA[2] = {A0, A1};
    const u16* gB[2] = {B0, B1};
    const int kg0 = kz * ksteps;

    auto stage = [&](int kg, int buf) {
        #pragma unroll
        for (int s = 0; s < 2; ++s) {
            const u16* g = gA[s] + ((size_t)(kg * rowsA + bm * 128 + wv * 32) * 32) + lane * 8;
            u16* l = &lds[buf][s * 4096 + wv * 1024 + lane * 8];
            GLL16(g, l);
            GLL16(g + 512, l + 512);
        }
        #pragma unroll
        for (int s = 0; s < 2; ++s) {
            const u16* g = gB[s] + ((size_t)(kg * rowsB + bn * 128 + wv * 32) * 32) + lane * 8;
            u16* l = &lds[buf][(2 + s) * 4096 + wv * 1024 + lane * 8];
            GLL16(g, l);
            GLL16(g + 512, l + 512);
        }
    };

    f32x4 acc[4][4];
    #pragma unroll
    for (int i = 0; i < 4; ++i)
        #pragma unroll
        for (int j = 0; j < 4; ++j) acc[i][j] = (f32x4){0.f, 0.f, 0.f, 0.f};

    stage(kg0, 0);
    asm volatile("s_waitcnt vmcnt(0)" ::: "memory");
    __builtin_amdgcn_s_barrier();

    int cur = 0;
    for (int ks = 0; ks < ksteps; ++ks) {
        // ---- issue next-tile staging FIRST (writes buf[cur^1]; the barrier
        // that ended the previous iteration guarantees all reads of it done)
        if (ks + 1 < ksteps) stage(kg0 + ks + 1, cur ^ 1);
        // ---- fragment ds_reads from lds[cur]
        f16x8 af[4][2], bf[4][2];
        #pragma unroll
        for (int i = 0; i < 4; ++i) {
            const int rowA = wrow + i * 16 + r15;
            const int offA = rowA * 64 + ((khi * 16) ^ (((rowA >> 1) & 3) << 4));
            const int rowB = wcol + i * 16 + r15;
            const int offB = rowB * 64 + ((khi * 16) ^ (((rowB >> 1) & 3) << 4));
            #pragma unroll
            for (int s = 0; s < 2; ++s) {
                af[i][s] = *(const f16x8*)((const char*)&lds[cur][s * 4096] + offA);
                bf[i][s] = *(const f16x8*)((const char*)&lds[cur][(2 + s) * 4096] + offB);
            }
        }
        // ---- 3 products: a0b0, a0b1, a1b0
        #pragma unroll
        for (int p = 0; p < 3; ++p) {
            const int pa = (p == 2) ? 1 : 0;
            const int pb = (p == 1) ? 1 : 0;
            #pragma unroll
            for (int i = 0; i < 4; ++i)
                #pragma unroll
                for (int j = 0; j < 4; ++j)
                    acc[i][j] = __builtin_amdgcn_mfma_f32_16x16x32_f16(
                        af[i][pa], bf[j][pb], acc[i][j], 0, 0, 0);
        }
        asm volatile("s_waitcnt vmcnt(0)" ::: "memory");
        __builtin_amdgcn_s_barrier();
        cur ^= 1;
    }

    float* pt = part + (size_t)kz * ((size_t)N_SAMP * ldc);
    #pragma unroll
    for (int i = 0; i < 4; ++i) {
        const int row0 = bm * 128 + wrow + i * 16 + khi * 4;
        #pragma unroll
        for (int j = 0; j < 4; ++j) {
            const int col = bn * 128 + wcol + j * 16 + r15;
            #pragma unroll
            for (int q = 0; q < 4; ++q)
                pt[(size_t)(row0 + q) * ldc + col] = acc[i][j][q];
        }
    }
}

// ---------------------------------------------------------------------------
// Kernel 2b: cls GEMM, 64x64 tiles for occupancy (0.8 GF over 256 blocks).
// X[1024,1024] x C^T[128,1024]. Grid (bn=2, bm=16, kz=8) = 256 blocks (%8==0).
// 4 waves x 32x32 quadrant (2x2 frags). LDS 2 x 16 KB dbuf. Same verified
// layout/swizzle/epilogue formulas as split_mfma.
// ---------------------------------------------------------------------------
__global__ __launch_bounds__(256, 4) void cls_mfma(
    const u16* __restrict__ A0, const u16* __restrict__ A1,
    const u16* __restrict__ B0, const u16* __restrict__ B1,
    float* __restrict__ part, int ksteps) {
    __shared__ u16 lds[2][4 * 2048];   // 2 phases x (A0|A1|B0|B1) x 4 KB
    const int nwg = gridDim.x * gridDim.y * gridDim.z;   // 256
    const int flat = blockIdx.x + gridDim.x * (blockIdx.y + gridDim.y * blockIdx.z);
    const int chunk = nwg >> 3;
    const int swz = (flat & 7) * chunk + (flat >> 3);
    const int bn = swz % gridDim.x;          // 0..1
    const int rest = swz / gridDim.x;
    const int bm = rest % gridDim.y;         // 0..15
    const int kz = rest / gridDim.y;

    const int tid = threadIdx.x, lane = tid & 63, wv = tid >> 6;
    const int wrow = (wv >> 1) * 32, wcol = (wv & 1) * 32;
    const int r15 = lane & 15, khi = lane >> 4;

    const u16* gA[2] = {A0, A1};
    const u16* gB[2] = {B0, B1};
    const int kg0 = kz * ksteps;

    auto stage = [&](int kg, int buf) {
        #pragma unroll
        for (int s = 0; s < 2; ++s) {
            const u16* g = gA[s] + ((size_t)(kg * 1024 + bm * 64 + wv * 16) * 32) + lane * 8;
            GLL16(g, &lds[buf][s * 2048 + wv * 512 + lane * 8]);
        }
        #pragma unroll
        for (int s = 0; s < 2; ++s) {
            const u16* g = gB[s] + ((size_t)(kg * 128 + bn * 64 + wv * 16) * 32) + lane * 8;
            GLL16(g, &lds[buf][(2 + s) * 2048 + wv * 512 + lane * 8]);
        }
    };

    f32x4 acc[2][2];
    #pragma unroll
    for (int i = 0; i < 2; ++i)
        #pragma unroll
        for (int j = 0; j < 2; ++j) acc[i][j] = (f32x4){0.f, 0.f, 0.f, 0.f};

    stage(kg0, 0);
    asm volatile("s_waitcnt vmcnt(0)" ::: "memory");
    __builtin_amdgcn_s_barrier();

    int cur = 0;
    for (int ks = 0; ks < ksteps; ++ks) {
        if (ks + 1 < ksteps) stage(kg0 + ks + 1, cur ^ 1);
        f16x8 af[2][2], bf[2][2];
        #pragma unroll
        for (int i = 0; i < 2; ++i) {
            const int rowA = wrow + i * 16 + r15;
            const int offA = rowA * 64 + ((khi * 16) ^ (((rowA >> 1) & 3) << 4));
            const int rowB = wcol + i * 16 + r15;
            const int offB = rowB * 64 + ((khi * 16) ^ (((rowB >> 1) & 3) << 4));
            #pragma unroll
            for (int s = 0; s < 2; ++s) {
                af[i][s] = *(const f16x8*)((const char*)&lds[cur][s * 2048] + offA);
                bf[i][s] = *(const f16x8*)((const char*)&lds[cur][(2 + s) * 2048] + offB);
            }
        }
        #pragma unroll
        for (int p = 0; p < 3; ++p) {
            const int pa = (p == 2) ? 1 : 0;
            const int pb = (p == 1) ? 1 : 0;
            #pragma unroll
            for (int i = 0; i < 2; ++i)
                #pragma unroll
                for (int j = 0; j < 2; ++j)
                    acc[i][j] = __builtin_amdgcn_mfma_f32_16x16x32_f16(
                        af[i][pa], bf[j][pb], acc[i][j], 0, 0, 0);
        }
        asm volatile("s_waitcnt vmcnt(0)" ::: "memory");
        __builtin_amdgcn_s_barrier();
        cur ^= 1;
    }

    float* pt = part + (size_t)kz * ((size_t)N_SAMP * 128);
    #pragma unroll
    for (int i = 0; i < 2; ++i) {
        const int row0 = bm * 64 + wrow + i * 16 + khi * 4;
        #pragma unroll
        for (int j = 0; j < 2; ++j) {
            const int col = bn * 64 + wcol + j * 16 + r15;
            #pragma unroll
            for (int q = 0; q < 4; ++q)
                pt[(size_t)(row0 + q) * 128 + col] = acc[i][j][q];
        }
    }
}

// ---------------------------------------------------------------------------
// Kernel 3: reduce fc1 split-K partials + bias + ReLU -> x fp32, and split2
// x into swizzled X0/X1 (rows=1024, K=1024) for the cls GEMM.
// ---------------------------------------------------------------------------
__global__ __launch_bounds__(256) void reduce_fc1(const float* __restrict__ part,
                                                  const float* __restrict__ bias,
                                                  float* __restrict__ x,
                                                  u16* __restrict__ x0,
                                                  u16* __restrict__ x1,
                                                  int nsplit) {
    const int i = blockIdx.x * 256 + threadIdx.x;     // float4 index, 262144 total
    const float4* p = reinterpret_cast<const float4*>(part);
    float4 s = p[i];
    for (int z = 1; z < nsplit; ++z) {
        const float4 t = p[(size_t)z * 262144 + i];
        s.x += t.x; s.y += t.y; s.z += t.z; s.w += t.w;
    }
    const float4 b = reinterpret_cast<const float4*>(bias)[i & 255];
    s.x = fmaxf(s.x + b.x, 0.f); s.y = fmaxf(s.y + b.y, 0.f);
    s.z = fmaxf(s.z + b.z, 0.f); s.w = fmaxf(s.w + b.w, 0.f);
    reinterpret_cast<float4*>(x)[i] = s;
    const int n = i >> 8, d0 = (i & 255) * 4;
    split2(s.x, x0, x1, split_idx_r(n, d0 + 0, N_SAMP));
    split2(s.y, x0, x1, split_idx_r(n, d0 + 1, N_SAMP));
    split2(s.z, x0, x1, split_idx_r(n, d0 + 2, N_SAMP));
    split2(s.w, x0, x1, split_idx_r(n, d0 + 3, N_SAMP));
}

// ---------------------------------------------------------------------------
// Kernel 4: fused decode + expert (verified rounds 4-6). Block per sample.
// ---------------------------------------------------------------------------
__global__ __launch_bounds__(128) void decode_expert(const float* __restrict__ part2,
                                                     const float* __restrict__ bp,
                                                     const float* __restrict__ bo,
                                                     const float* __restrict__ x,
                                                     const float* __restrict__ wpos,
                                                     const float* __restrict__ bpos,
                                                     const float* __restrict__ wori,
                                                     const float* __restrict__ bori,
                                                     float* __restrict__ pose_cls,
                                                     float* __restrict__ pose,
                                                     int nsplit) {
    const int n = blockIdx.x, t = threadIdx.x;
    __shared__ float xs[LATENT_D];
    __shared__ int esh[2];

    const float4* x4 = reinterpret_cast<const float4*>(x + (size_t)n * LATENT_D);
    float4* xs4 = reinterpret_cast<float4*>(xs);
    xs4[t] = x4[t];
    xs4[t + 128] = x4[t + 128];

    float s = (t < 64) ? bp[t] : bo[t - 64];
    for (int z = 0; z < nsplit; ++z)
        s += part2[(size_t)z * (N_SAMP * 128) + (size_t)n * 128 + t];
    const float sig = 1.0f / (1.0f + expf(-s));
    const int head = t >> 6, c = t & 63;
    pose_cls[(size_t)n * (NCLS * 2) + c * 2 + head] = sig;

    const unsigned long long mask = __ballot(s > 0.0f);
    if (c == 0) {
        const unsigned long long inv = ~mask;
        const int run = inv ? __builtin_ctzll(inv) : 64;
        const int lab = run - 1;
        esh[head] = lab > 0 ? lab : 0;
    }
    __syncthreads();

    const int e = esh[head];
    const int nk = head ? 4 : 3;
    for (int kk = 0; kk < nk; ++kk) {
        const float* wr = head ? wori + (size_t)(e * 4 + kk) * LATENT_D
                               : wpos + (size_t)(e * 3 + kk) * LATENT_D;
        const float bb = head ? bori[e * 4 + kk] : bpos[e * 3 + kk];
        const float4* w4 = reinterpret_cast<const float4*>(wr);
        float s2 = 0.f;
        #pragma unroll
        for (int i = 0; i < 4; ++i) {
            const int q = c + i * 64;
            const float4 a = w4[q];
            s2 += a.x * xs[q * 4] + a.y * xs[q * 4 + 1] + a.z * xs[q * 4 + 2] + a.w * xs[q * 4 + 3];
        }
        #pragma unroll
        for (int off = 32; off > 0; off >>= 1) s2 += __shfl_down(s2, off);
        if (c == 0) pose[(size_t)n * 7 + (head ? 3 + kk : kk)] = s2 + bb;
    }
}

// ---------------------------------------------------------------------------
extern "C" void kernel_launch(void* const* d_in, const int* in_sizes, int n_in,
                              void* d_out, int out_size, void* d_ws, size_t ws_size,
                              hipStream_t stream) {
    const float* feat   = (const float*)d_in[0];
    const float* fc1_w  = (const float*)d_in[1];
    const float* fc1_b  = (const float*)d_in[2];
    const float* cpw    = (const float*)d_in[3];
    const float* cpb    = (const float*)d_in[4];
    const float* cow    = (const float*)d_in[5];
    const float* cob    = (const float*)d_in[6];
    const float* rpw    = (const float*)d_in[7];
    const float* rpb    = (const float*)d_in[8];
    const float* row_   = (const float*)d_in[9];
    const float* rob    = (const float*)d_in[10];

    float* out = (float*)d_out;
    float* pose     = out;                          // [1024][7]
    float* pose_cls = out + (size_t)N_SAMP * 7;     // [1024][64][2]

    char* ws = (char*)d_ws;
    const size_t MB = (size_t)1 << 20;
    size_t off = 0;
    auto take = [&](size_t bytes) { char* p = ws + off; off += (bytes + 255) & ~(size_t)255; return p; };

    u16* A0 = (u16*)take(4 * MB);      // 64kg x 1024 x 32 x 2B
    u16* A1 = (u16*)take(4 * MB);
    u16* B0 = (u16*)take(4 * MB);
    u16* B1 = (u16*)take(4 * MB);
    u16* C0 = (u16*)take(256 * 1024);  // 32kg x 128 x 32 x 2B
    u16* C1 = (u16*)take(256 * 1024);
    u16* X0 = (u16*)take(2 * MB);      // 32kg x 1024 x 32 x 2B
    u16* X1 = (u16*)take(2 * MB);
    float* x = (float*)take(4 * MB);

    int nsplit = 8;
    while (nsplit > 1 && off + (size_t)nsplit * 4 * MB + 5 * MB > ws_size) nsplit >>= 1;
    float* part = (float*)take((size_t)nsplit * 4 * MB);
    int nsplit_c = 8;
    while (nsplit_c > 1 && off + (size_t)nsplit_c * 512 * 1024 > ws_size) nsplit_c >>= 1;
    float* part2 = (float*)take((size_t)nsplit_c * 512 * 1024);

    // 1. fused prep: pool->A splits, fc1_w->B splits, cls->C splits
    prep_kernel<<<16896, 256, 0, stream>>>(feat, fc1_w, cpw, cow,
                                           A0, A1, B0, B1, C0, C1);
    // 2. fc1: M=1024, N=1024, K=2048  (512 blocks, %8==0 for XCD swizzle)
    split_mfma<<<dim3(8, 8, nsplit), 256, 0, stream>>>(
        A0, A1, B0, B1, part, 64 / nsplit, N_SAMP, LATENT_D, LATENT_D);
    // 3. reduce + bias + relu + x-split
    reduce_fc1<<<1024, 256, 0, stream>>>(part, fc1_b, x, X0, X1, nsplit);
    // 4. cls: M=1024, N=128, K=1024; 64x64 tiles, 256 blocks
    cls_mfma<<<dim3(2, 16, nsplit_c), 256, 0, stream>>>(
        X0, X1, C0, C1, part2, 32 / nsplit_c);
    // 5. decode + expert
    decode_expert<<<N_SAMP, 128, 0, stream>>>(part2, cpb, cob, x, rpw, rpb, row_, rob,
                                              pose_cls, pose, nsplit_c);
}

// Round 8
// 126.320 us; speedup vs baseline: 2.4242x; 1.0181x over previous
//
#include <hip/hip_runtime.h>
#include <hip/hip_bf16.h>

#define N_SAMP   1024
#define BD       2048
#define LATENT_D 1024
#define NCLS     64
#define HW       49

typedef __attribute__((ext_vector_type(8))) _Float16 f16x8;
typedef __attribute__((ext_vector_type(4))) float f32x4;
typedef unsigned short u16;

// ---------------------------------------------------------------------------
// Split-fp16 tiled+swizzled layout (rounds 2-7, verified):
//   segment (kg = k>>5, row) = 32 ushorts (64 B) at ((kg*rows + row)*32),
//   byte within segment: c2 = (ke*2) ^ (((row>>1)&3)<<4).
// 128/64-row x 32-k tiles are contiguous chunks; linear global_load_lds lands
// pre-swizzled for conflict-light ds_read_b128 (G21 source==read perm).
// fp16 2-way split, 3 products (a0b0+a0b1+a1b0): dropped a1b1 <= 2^-22 rel
// -> ~5e-8 logit error, below fp32's own reorder noise. fp32-grade.
// ---------------------------------------------------------------------------
__device__ __forceinline__ size_t split_idx_r(int row, int k, int rows) {
    const int kg = k >> 5, ke = k & 31;
    const int c2 = (ke * 2) ^ (((row >> 1) & 3) << 4);
    return ((size_t)(kg * rows + row) * 32) + (c2 >> 1);
}

__device__ __forceinline__ void split2(float v, u16* p0, u16* p1, size_t idx) {
    _Float16 h0 = (_Float16)v;
    _Float16 h1 = (_Float16)(v - (float)h0);
    p0[idx] = *(u16*)&h0;
    p1[idx] = *(u16*)&h1;
}

#define GLL16(g, l) __builtin_amdgcn_global_load_lds( \
    (const __attribute__((address_space(1))) void*)(g), \
    (__attribute__((address_space(3))) void*)(l), 16, 0, 0)

// ---------------------------------------------------------------------------
// Kernel 1 (fused prep):
//  blocks [0, 8192):      avg-pool 7x7 -> split2 -> A0/A1 (rows=1024, K=2048).
//  blocks [8192, 16384):  fc1_w split -> B0/B1 (rows=1024, K=2048).
//  blocks [16384, 16896): cls weights [64 pos | 64 orient] -> C0/C1 (rows=128).
// ---------------------------------------------------------------------------
__global__ __launch_bounds__(256) void prep_kernel(const float* __restrict__ feat,
                                                   const float* __restrict__ W,
                                                   const float* __restrict__ Wp,
                                                   const float* __restrict__ Wo,
                                                   u16* __restrict__ a0,
                                                   u16* __restrict__ a1,
                                                   u16* __restrict__ b0,
                                                   u16* __restrict__ b1,
                                                   u16* __restrict__ c0,
                                                   u16* __restrict__ c1) {
    __shared__ float buf[256 * HW];                  // 50176 B (pool blocks only)
    const int b = blockIdx.x;
    const int tid = threadIdx.x;
    if (b < 8192) {
        const int lane = tid & 63, wv = tid >> 6;
        const float* src = feat + (size_t)b * (256 * HW);
        for (int c = wv; c < 49; c += 4)
            GLL16(src + c * 256 + lane * 4, (char*)buf + c * 1024 + lane * 16);
        asm volatile("s_waitcnt vmcnt(0)" ::: "memory");
        __syncthreads();
        const float* p = buf + tid * HW;
        float s = 0.f;
        #pragma unroll
        for (int k = 0; k < HW; ++k) s += p[k];
        const float v = s * (1.0f / 49.0f);
        const int n = b >> 3;
        const int d = (b & 7) * 256 + tid;
        split2(v, a0, a1, split_idx_r(n, d, N_SAMP));
    } else if (b < 16384) {
        const int b2 = b - 8192;
        const int row = b2 >> 3;
        const int d = (b2 & 7) * 256 + tid;
        split2(W[(size_t)row * BD + d], b0, b1, split_idx_r(row, d, LATENT_D));
    } else {
        const int b2 = b - 16384;
        const int row = b2 >> 2;                            // 0..127
        const int d = (b2 & 3) * 256 + tid;                 // 0..1023
        const float v = row < 64 ? Wp[(size_t)row * LATENT_D + d]
                                 : Wo[(size_t)(row - 64) * LATENT_D + d];
        split2(v, c0, c1, split_idx_r(row, d, 128));
    }
}

// ---------------------------------------------------------------------------
// Kernel 2: fc1 split-fp16 MFMA GEMM, 3 products, counted-vmcnt pipeline (T4).
// Tile 128x128, BK=32, 4 waves x (64x64 quadrant of 4x4 16x16x32 frags).
// Per K-step: stage(t+1) [8 loads] -> vmcnt(8) waits only tile t's loads
// (issued one full iter earlier; latency hidden under prior ds_read+MFMA)
// -> barrier (cross-wave) -> sched_barrier (rule #18) -> ds_read+MFMA ->
// barrier (WAR guard). Final iter: vmcnt(0). XCD-bijective swizzle (nwg%8==0).
// ---------------------------------------------------------------------------
__global__ __launch_bounds__(256, 2) void split_mfma(
    const u16* __restrict__ A0, const u16* __restrict__ A1,
    const u16* __restrict__ B0, const u16* __restrict__ B1,
    float* __restrict__ part, int ksteps, int rowsA, int rowsB, int ldc) {
    __shared__ u16 lds[2][4 * 4096];   // 2 phases x (A0|A1|B0|B1) x 8 KB
    const int nwg = gridDim.x * gridDim.y * gridDim.z;
    const int flat = blockIdx.x + gridDim.x * (blockIdx.y + gridDim.y * blockIdx.z);
    const int chunk = nwg >> 3;
    const int swz = (flat & 7) * chunk + (flat >> 3);
    const int bn = swz % gridDim.x;
    const int rest = swz / gridDim.x;
    const int bm = rest % gridDim.y;
    const int kz = rest / gridDim.y;

    const int tid = threadIdx.x, lane = tid & 63, wv = tid >> 6;
    const int wrow = (wv >> 1) * 64, wcol = (wv & 1) * 64;
    const int r15 = lane & 15, khi = lane >> 4;

    const u16* gA[2] = {A0, A1};
    const u16* gB[2] = {B0, B1};
    const int kg0 = kz * ksteps;

    auto stage = [&](int kg, int buf) {
        #pragma unroll
        for (int s = 0; s < 2; ++s) {
            const u16* g = gA[s] + ((size_t)(kg * rowsA + bm * 128 + wv * 32) * 32) + lane * 8;
            u16* l = &lds[buf][s * 4096 + wv * 1024 + lane * 8];
            GLL16(g, l);
            GLL16(g + 512, l + 512);
        }
        #pragma unroll
        for (int s = 0; s < 2; ++s) {
            const u16* g = gB[s] + ((size_t)(kg * rowsB + bn * 128 + wv * 32) * 32) + lane * 8;
            u16* l = &lds[buf][(2 + s) * 4096 + wv * 1024 + lane * 8];
            GLL16(g, l);
            GLL16(g + 512, l + 512);
        }
    };

    f32x4 acc[4][4];
    #pragma unroll
    for (int i = 0; i < 4; ++i)
        #pragma unroll
        for (int j = 0; j < 4; ++j) acc[i][j] = (f32x4){0.f, 0.f, 0.f, 0.f};

    stage(kg0, 0);   // tile 0 -> buf0; NOT drained here (counted wait in iter 0)

    int cur = 0;
    for (int ks = 0; ks < ksteps; ++ks) {
        if (ks + 1 < ksteps) {
            stage(kg0 + ks + 1, cur ^ 1);                  // 8 more in flight
            asm volatile("s_waitcnt vmcnt(8)" ::: "memory");  // tile ks landed (this wave)
        } else {
            asm volatile("s_waitcnt vmcnt(0)" ::: "memory");
        }
        __builtin_amdgcn_s_barrier();        // all waves' tile-ks loads landed
        __builtin_amdgcn_sched_barrier(0);   // no hoisting across the wait
        // ---- fragment ds_reads from lds[cur]
        f16x8 af[4][2], bf[4][2];
        #pragma unroll
        for (int i = 0; i < 4; ++i) {
            const int rowA = wrow + i * 16 + r15;
            const int offA = rowA * 64 + ((khi * 16) ^ (((rowA >> 1) & 3) << 4));
            const int rowB = wcol + i * 16 + r15;
            const int offB = rowB * 64 + ((khi * 16) ^ (((rowB >> 1) & 3) << 4));
            #pragma unroll
            for (int s = 0; s < 2; ++s) {
                af[i][s] = *(const f16x8*)((const char*)&lds[cur][s * 4096] + offA);
                bf[i][s] = *(const f16x8*)((const char*)&lds[cur][(2 + s) * 4096] + offB);
            }
        }
        // ---- 3 products: a0b0, a0b1, a1b0
        #pragma unroll
        for (int p = 0; p < 3; ++p) {
            const int pa = (p == 2) ? 1 : 0;
            const int pb = (p == 1) ? 1 : 0;
            #pragma unroll
            for (int i = 0; i < 4; ++i)
                #pragma unroll
                for (int j = 0; j < 4; ++j)
                    acc[i][j] = __builtin_amdgcn_mfma_f32_16x16x32_f16(
                        af[i][pa], bf[j][pb], acc[i][j], 0, 0, 0);
        }
        __builtin_amdgcn_s_barrier();        // reads done before next overwrite
        cur ^= 1;
    }

    float* pt = part + (size_t)kz * ((size_t)N_SAMP * ldc);
    #pragma unroll
    for (int i = 0; i < 4; ++i) {
        const int row0 = bm * 128 + wrow + i * 16 + khi * 4;
        #pragma unroll
        for (int j = 0; j < 4; ++j) {
            const int col = bn * 128 + wcol + j * 16 + r15;
            #pragma unroll
            for (int q = 0; q < 4; ++q)
                pt[(size_t)(row0 + q) * ldc + col] = acc[i][j][q];
        }
    }
}

// ---------------------------------------------------------------------------
// Kernel 2b: cls GEMM, 64x64 tiles, counted-vmcnt pipeline (vmcnt(4)).
// Grid (2,16,8) = 256 blocks. 4 waves x 32x32 quadrant (2x2 frags).
// ---------------------------------------------------------------------------
__global__ __launch_bounds__(256, 4) void cls_mfma(
    const u16* __restrict__ A0, const u16* __restrict__ A1,
    const u16* __restrict__ B0, const u16* __restrict__ B1,
    float* __restrict__ part, int ksteps) {
    __shared__ u16 lds[2][4 * 2048];   // 2 phases x (A0|A1|B0|B1) x 4 KB
    const int nwg = gridDim.x * gridDim.y * gridDim.z;   // 256
    const int flat = blockIdx.x + gridDim.x * (blockIdx.y + gridDim.y * blockIdx.z);
    const int chunk = nwg >> 3;
    const int swz = (flat & 7) * chunk + (flat >> 3);
    const int bn = swz % gridDim.x;
    const int rest = swz / gridDim.x;
    const int bm = rest % gridDim.y;
    const int kz = rest / gridDim.y;

    const int tid = threadIdx.x, lane = tid & 63, wv = tid >> 6;
    const int wrow = (wv >> 1) * 32, wcol = (wv & 1) * 32;
    const int r15 = lane & 15, khi = lane >> 4;

    const u16* gA[2] = {A0, A1};
    const u16* gB[2] = {B0, B1};
    const int kg0 = kz * ksteps;

    auto stage = [&](int kg, int buf) {
        #pragma unroll
        for (int s = 0; s < 2; ++s) {
            const u16* g = gA[s] + ((size_t)(kg * 1024 + bm * 64 + wv * 16) * 32) + lane * 8;
            GLL16(g, &lds[buf][s * 2048 + wv * 512 + lane * 8]);
        }
        #pragma unroll
        for (int s = 0; s < 2; ++s) {
            const u16* g = gB[s] + ((size_t)(kg * 128 + bn * 64 + wv * 16) * 32) + lane * 8;
            GLL16(g, &lds[buf][(2 + s) * 2048 + wv * 512 + lane * 8]);
        }
    };

    f32x4 acc[2][2];
    #pragma unroll
    for (int i = 0; i < 2; ++i)
        #pragma unroll
        for (int j = 0; j < 2; ++j) acc[i][j] = (f32x4){0.f, 0.f, 0.f, 0.f};

    stage(kg0, 0);

    int cur = 0;
    for (int ks = 0; ks < ksteps; ++ks) {
        if (ks + 1 < ksteps) {
            stage(kg0 + ks + 1, cur ^ 1);
            asm volatile("s_waitcnt vmcnt(4)" ::: "memory");
        } else {
            asm volatile("s_waitcnt vmcnt(0)" ::: "memory");
        }
        __builtin_amdgcn_s_barrier();
        __builtin_amdgcn_sched_barrier(0);
        f16x8 af[2][2], bf[2][2];
        #pragma unroll
        for (int i = 0; i < 2; ++i) {
            const int rowA = wrow + i * 16 + r15;
            const int offA = rowA * 64 + ((khi * 16) ^ (((rowA >> 1) & 3) << 4));
            const int rowB = wcol + i * 16 + r15;
            const int offB = rowB * 64 + ((khi * 16) ^ (((rowB >> 1) & 3) << 4));
            #pragma unroll
            for (int s = 0; s < 2; ++s) {
                af[i][s] = *(const f16x8*)((const char*)&lds[cur][s * 2048] + offA);
                bf[i][s] = *(const f16x8*)((const char*)&lds[cur][(2 + s) * 2048] + offB);
            }
        }
        #pragma unroll
        for (int p = 0; p < 3; ++p) {
            const int pa = (p == 2) ? 1 : 0;
            const int pb = (p == 1) ? 1 : 0;
            #pragma unroll
            for (int i = 0; i < 2; ++i)
                #pragma unroll
                for (int j = 0; j < 2; ++j)
                    acc[i][j] = __builtin_amdgcn_mfma_f32_16x16x32_f16(
                        af[i][pa], bf[j][pb], acc[i][j], 0, 0, 0);
        }
        __builtin_amdgcn_s_barrier();
        cur ^= 1;
    }

    float* pt = part + (size_t)kz * ((size_t)N_SAMP * 128);
    #pragma unroll
    for (int i = 0; i < 2; ++i) {
        const int row0 = bm * 64 + wrow + i * 16 + khi * 4;
        #pragma unroll
        for (int j = 0; j < 2; ++j) {
            const int col = bn * 64 + wcol + j * 16 + r15;
            #pragma unroll
            for (int q = 0; q < 4; ++q)
                pt[(size_t)(row0 + q) * 128 + col] = acc[i][j][q];
        }
    }
}

// ---------------------------------------------------------------------------
// Kernel 3: reduce fc1 split-K partials + bias + ReLU -> x fp32, and split2
// x into swizzled X0/X1 (rows=1024, K=1024) for the cls GEMM.
// ---------------------------------------------------------------------------
__global__ __launch_bounds__(256) void reduce_fc1(const float* __restrict__ part,
                                                  const float* __restrict__ bias,
                                                  float* __restrict__ x,
                                                  u16* __restrict__ x0,
                                                  u16* __restrict__ x1,
                                                  int nsplit) {
    const int i = blockIdx.x * 256 + threadIdx.x;     // float4 index, 262144 total
    const float4* p = reinterpret_cast<const float4*>(part);
    float4 s = p[i];
    for (int z = 1; z < nsplit; ++z) {
        const float4 t = p[(size_t)z * 262144 + i];
        s.x += t.x; s.y += t.y; s.z += t.z; s.w += t.w;
    }
    const float4 b = reinterpret_cast<const float4*>(bias)[i & 255];
    s.x = fmaxf(s.x + b.x, 0.f); s.y = fmaxf(s.y + b.y, 0.f);
    s.z = fmaxf(s.z + b.z, 0.f); s.w = fmaxf(s.w + b.w, 0.f);
    reinterpret_cast<float4*>(x)[i] = s;
    const int n = i >> 8, d0 = (i & 255) * 4;
    split2(s.x, x0, x1, split_idx_r(n, d0 + 0, N_SAMP));
    split2(s.y, x0, x1, split_idx_r(n, d0 + 1, N_SAMP));
    split2(s.z, x0, x1, split_idx_r(n, d0 + 2, N_SAMP));
    split2(s.w, x0, x1, split_idx_r(n, d0 + 3, N_SAMP));
}

// ---------------------------------------------------------------------------
// Kernel 4: fused decode + expert (verified rounds 4-7). Block per sample.
// ---------------------------------------------------------------------------
__global__ __launch_bounds__(128) void decode_expert(const float* __restrict__ part2,
                                                     const float* __restrict__ bp,
                                                     const float* __restrict__ bo,
                                                     const float* __restrict__ x,
                                                     const float* __restrict__ wpos,
                                                     const float* __restrict__ bpos,
                                                     const float* __restrict__ wori,
                                                     const float* __restrict__ bori,
                                                     float* __restrict__ pose_cls,
                                                     float* __restrict__ pose,
                                                     int nsplit) {
    const int n = blockIdx.x, t = threadIdx.x;
    __shared__ float xs[LATENT_D];
    __shared__ int esh[2];

    const float4* x4 = reinterpret_cast<const float4*>(x + (size_t)n * LATENT_D);
    float4* xs4 = reinterpret_cast<float4*>(xs);
    xs4[t] = x4[t];
    xs4[t + 128] = x4[t + 128];

    float s = (t < 64) ? bp[t] : bo[t - 64];
    for (int z = 0; z < nsplit; ++z)
        s += part2[(size_t)z * (N_SAMP * 128) + (size_t)n * 128 + t];
    const float sig = 1.0f / (1.0f + expf(-s));
    const int head = t >> 6, c = t & 63;
    pose_cls[(size_t)n * (NCLS * 2) + c * 2 + head] = sig;

    const unsigned long long mask = __ballot(s > 0.0f);
    if (c == 0) {
        const unsigned long long inv = ~mask;
        const int run = inv ? __builtin_ctzll(inv) : 64;
        const int lab = run - 1;
        esh[head] = lab > 0 ? lab : 0;
    }
    __syncthreads();

    const int e = esh[head];
    const int nk = head ? 4 : 3;
    for (int kk = 0; kk < nk; ++kk) {
        const float* wr = head ? wori + (size_t)(e * 4 + kk) * LATENT_D
                               : wpos + (size_t)(e * 3 + kk) * LATENT_D;
        const float bb = head ? bori[e * 4 + kk] : bpos[e * 3 + kk];
        const float4* w4 = reinterpret_cast<const float4*>(wr);
        float s2 = 0.f;
        #pragma unroll
        for (int i = 0; i < 4; ++i) {
            const int q = c + i * 64;
            const float4 a = w4[q];
            s2 += a.x * xs[q * 4] + a.y * xs[q * 4 + 1] + a.z * xs[q * 4 + 2] + a.w * xs[q * 4 + 3];
        }
        #pragma unroll
        for (int off = 32; off > 0; off >>= 1) s2 += __shfl_down(s2, off);
        if (c == 0) pose[(size_t)n * 7 + (head ? 3 + kk : kk)] = s2 + bb;
    }
}

// ---------------------------------------------------------------------------
extern "C" void kernel_launch(void* const* d_in, const int* in_sizes, int n_in,
                              void* d_out, int out_size, void* d_ws, size_t ws_size,
                              hipStream_t stream) {
    const float* feat   = (const float*)d_in[0];
    const float* fc1_w  = (const float*)d_in[1];
    const float* fc1_b  = (const float*)d_in[2];
    const float* cpw    = (const float*)d_in[3];
    const float* cpb    = (const float*)d_in[4];
    const float* cow    = (const float*)d_in[5];
    const float* cob    = (const float*)d_in[6];
    const float* rpw    = (const float*)d_in[7];
    const float* rpb    = (const float*)d_in[8];
    const float* row_   = (const float*)d_in[9];
    const float* rob    = (const float*)d_in[10];

    float* out = (float*)d_out;
    float* pose     = out;                          // [1024][7]
    float* pose_cls = out + (size_t)N_SAMP * 7;     // [1024][64][2]

    char* ws = (char*)d_ws;
    const size_t MB = (size_t)1 << 20;
    size_t off = 0;
    auto take = [&](size_t bytes) { char* p = ws + off; off += (bytes + 255) & ~(size_t)255; return p; };

    u16* A0 = (u16*)take(4 * MB);      // 64kg x 1024 x 32 x 2B
    u16* A1 = (u16*)take(4 * MB);
    u16* B0 = (u16*)take(4 * MB);
    u16* B1 = (u16*)take(4 * MB);
    u16* C0 = (u16*)take(256 * 1024);  // 32kg x 128 x 32 x 2B
    u16* C1 = (u16*)take(256 * 1024);
    u16* X0 = (u16*)take(2 * MB);      // 32kg x 1024 x 32 x 2B
    u16* X1 = (u16*)take(2 * MB);
    float* x = (float*)take(4 * MB);

    int nsplit = 8;
    while (nsplit > 1 && off + (size_t)nsplit * 4 * MB + 5 * MB > ws_size) nsplit >>= 1;
    float* part = (float*)take((size_t)nsplit * 4 * MB);
    int nsplit_c = 8;
    while (nsplit_c > 1 && off + (size_t)nsplit_c * 512 * 1024 > ws_size) nsplit_c >>= 1;
    float* part2 = (float*)take((size_t)nsplit_c * 512 * 1024);

    // 1. fused prep: pool->A splits, fc1_w->B splits, cls->C splits
    prep_kernel<<<16896, 256, 0, stream>>>(feat, fc1_w, cpw, cow,
                                           A0, A1, B0, B1, C0, C1);
    // 2. fc1: M=1024, N=1024, K=2048  (512 blocks, %8==0 for XCD swizzle)
    split_mfma<<<dim3(8, 8, nsplit), 256, 0, stream>>>(
        A0, A1, B0, B1, part, 64 / nsplit, N_SAMP, LATENT_D, LATENT_D);
    // 3. reduce + bias + relu + x-split
    reduce_fc1<<<1024, 256, 0, stream>>>(part, fc1_b, x, X0, X1, nsplit);
    // 4. cls: M=1024, N=128, K=1024; 64x64 tiles, 256 blocks
    cls_mfma<<<dim3(2, 16, nsplit_c), 256, 0, stream>>>(
        X0, X1, C0, C1, part2, 32 / nsplit_c);
    // 5. decode + expert
    decode_expert<<<N_SAMP, 128, 0, stream>>>(part2, cpb, cob, x, rpw, rpb, row_, rob,
                                              pose_cls, pose, nsplit_c);
}